// Round 1
// baseline (487.685 us; speedup 1.0000x reference)
//
#include <hip/hip_runtime.h>
#include <math.h>

#define BSZ   16
#define LSEQ  1024
#define TGT   256
#define HID   512
#define TV    2000
#define VOC   3000
#define SRC   2048
#define SALL  2049
#define APITCH 2064   // padded atten row pitch (float4-aligned)

static __device__ __forceinline__ float gelu_exact(float x) {
    return 0.5f * x * (1.0f + erff(x * 0.70710678118654752f));
}

// ---------------- block reductions (256 threads = 4 waves) ----------------
__device__ __forceinline__ float blockReduceMax(float v, float* red) {
    #pragma unroll
    for (int o = 32; o > 0; o >>= 1) v = fmaxf(v, __shfl_down(v, o, 64));
    const int wid = threadIdx.x >> 6, lane = threadIdx.x & 63;
    __syncthreads();                 // protect red from previous use
    if (lane == 0) red[wid] = v;
    __syncthreads();
    return fmaxf(fmaxf(red[0], red[1]), fmaxf(red[2], red[3]));
}
__device__ __forceinline__ float blockReduceSum(float v, float* red) {
    #pragma unroll
    for (int o = 32; o > 0; o >>= 1) v += __shfl_down(v, o, 64);
    const int wid = threadIdx.x >> 6, lane = threadIdx.x & 63;
    __syncthreads();
    if (lane == 0) red[wid] = v;
    __syncthreads();
    return red[0] + red[1] + red[2] + red[3];
}

// ---------------- GEMM 1: keys = reshape(memory_raw @ Wk + bk) ----------------
// A: (16384, 512) row-major, B: (512, 1024) row-major, out: keys (16, 2049, 512)
// (b,l,n) -> keys[b][2*l + n/512][n%512]  => contiguous within each m-row.
__global__ __launch_bounds__(256) void gemm_keys(
    const float* __restrict__ A, const float* __restrict__ B,
    const float* __restrict__ bias, float* __restrict__ keys)
{
    __shared__ float As[16][68];
    __shared__ float Bs[16][68];
    const int tid = threadIdx.x;
    const int m0 = blockIdx.y * 64;
    const int n0 = blockIdx.x * 64;
    const int tx = tid & 15, ty = tid >> 4;
    const int am = tid >> 2, ak = (tid & 3) * 4;   // A: 64 m x 16 k per step
    const int bk_ = tid >> 4, bn = (tid & 15) * 4; // B: 16 k x 64 n per step
    float acc[4][4] = {};
    const int K = 512, NB = 1024;
    for (int k0 = 0; k0 < K; k0 += 16) {
        float4 av = *(const float4*)&A[(size_t)(m0 + am) * K + k0 + ak];
        float4 bv = *(const float4*)&B[(size_t)(k0 + bk_) * NB + n0 + bn];
        __syncthreads();
        As[ak + 0][am] = av.x; As[ak + 1][am] = av.y;
        As[ak + 2][am] = av.z; As[ak + 3][am] = av.w;
        *(float4*)&Bs[bk_][bn] = bv;
        __syncthreads();
        #pragma unroll
        for (int kk = 0; kk < 16; ++kk) {
            float4 a4 = *(const float4*)&As[kk][tx * 4];
            float4 b4 = *(const float4*)&Bs[kk][ty * 4];
            float a[4] = {a4.x, a4.y, a4.z, a4.w};
            float b[4] = {b4.x, b4.y, b4.z, b4.w};
            #pragma unroll
            for (int i = 0; i < 4; ++i)
                #pragma unroll
                for (int j = 0; j < 4; ++j) acc[i][j] += a[i] * b[j];
        }
    }
    float4 bv = *(const float4*)&bias[n0 + ty * 4];
    #pragma unroll
    for (int i = 0; i < 4; ++i) {
        int m = m0 + tx * 4 + i;
        int b = m >> 10, l = m & 1023;
        size_t base = (size_t)b * SALL * HID + (size_t)l * 1024 + n0 + ty * 4;
        float4 o = make_float4(acc[i][0] + bv.x, acc[i][1] + bv.y,
                               acc[i][2] + bv.z, acc[i][3] + bv.w);
        *(float4*)&keys[base] = o;
    }
}

// ---------------- sentinel row fill: keys[b][2048][:] = sentinel ----------------
__global__ void fill_sentinel(const float* __restrict__ sent, float* __restrict__ keys) {
    const int b = blockIdx.x;
    for (int h = threadIdx.x; h < HID; h += 256)
        keys[(size_t)b * SALL * HID + (size_t)SRC * HID + h] = sent[h];
}

// ---------------- GEMM 2: query = gelu(feature @ Wq + bq) ----------------
__global__ __launch_bounds__(256) void gemm_query(
    const float* __restrict__ A, const float* __restrict__ B,
    const float* __restrict__ bias, float* __restrict__ Q)
{
    __shared__ float As[16][68];
    __shared__ float Bs[16][68];
    const int tid = threadIdx.x;
    const int m0 = blockIdx.y * 64;
    const int n0 = blockIdx.x * 64;
    const int tx = tid & 15, ty = tid >> 4;
    const int am = tid >> 2, ak = (tid & 3) * 4;
    const int bk_ = tid >> 4, bn = (tid & 15) * 4;
    float acc[4][4] = {};
    const int K = 512, NB = 512;
    for (int k0 = 0; k0 < K; k0 += 16) {
        float4 av = *(const float4*)&A[(size_t)(m0 + am) * K + k0 + ak];
        float4 bv = *(const float4*)&B[(size_t)(k0 + bk_) * NB + n0 + bn];
        __syncthreads();
        As[ak + 0][am] = av.x; As[ak + 1][am] = av.y;
        As[ak + 2][am] = av.z; As[ak + 3][am] = av.w;
        *(float4*)&Bs[bk_][bn] = bv;
        __syncthreads();
        #pragma unroll
        for (int kk = 0; kk < 16; ++kk) {
            float4 a4 = *(const float4*)&As[kk][tx * 4];
            float4 b4 = *(const float4*)&Bs[kk][ty * 4];
            float a[4] = {a4.x, a4.y, a4.z, a4.w};
            float b[4] = {b4.x, b4.y, b4.z, b4.w};
            #pragma unroll
            for (int i = 0; i < 4; ++i)
                #pragma unroll
                for (int j = 0; j < 4; ++j) acc[i][j] += a[i] * b[j];
        }
    }
    float4 bv = *(const float4*)&bias[n0 + ty * 4];
    #pragma unroll
    for (int i = 0; i < 4; ++i) {
        int m = m0 + tx * 4 + i;
        float vals[4] = {acc[i][0] + bv.x, acc[i][1] + bv.y,
                         acc[i][2] + bv.z, acc[i][3] + bv.w};
        float4 o = make_float4(gelu_exact(vals[0]), gelu_exact(vals[1]),
                               gelu_exact(vals[2]), gelu_exact(vals[3]));
        *(float4*)&Q[(size_t)m * NB + n0 + ty * 4] = o;
    }
}

// ---------------- GEMM 3: atten[b][t][s] = q[b,t,:] . keys[b,s,:] / sqrt(512) ----------------
__global__ __launch_bounds__(256) void gemm_atten(
    const float* __restrict__ Q, const float* __restrict__ Keys,
    float* __restrict__ atten)
{
    __shared__ float As[16][68];
    __shared__ float Bs[16][68];
    const int tid = threadIdx.x;
    const int b = blockIdx.z;
    const int m0 = blockIdx.y * 64;   // t tile (256 -> 4)
    const int n0 = blockIdx.x * 64;   // s tile (2049 -> 33)
    const int tx = tid & 15, ty = tid >> 4;
    const int am = tid >> 2, ak = (tid & 3) * 4;
    const int sn = tid >> 2, hk = (tid & 3) * 4;   // B: 64 s x 16 h per step
    const float* Ab = Q + (size_t)b * TGT * HID;
    const float* Kb = Keys + (size_t)b * SALL * HID;
    float acc[4][4] = {};
    for (int k0 = 0; k0 < HID; k0 += 16) {
        float4 av = *(const float4*)&Ab[(size_t)(m0 + am) * HID + k0 + ak];
        float4 kv = make_float4(0.f, 0.f, 0.f, 0.f);
        if (n0 + sn < SALL)
            kv = *(const float4*)&Kb[(size_t)(n0 + sn) * HID + k0 + hk];
        __syncthreads();
        As[ak + 0][am] = av.x; As[ak + 1][am] = av.y;
        As[ak + 2][am] = av.z; As[ak + 3][am] = av.w;
        Bs[hk + 0][sn] = kv.x; Bs[hk + 1][sn] = kv.y;
        Bs[hk + 2][sn] = kv.z; Bs[hk + 3][sn] = kv.w;
        __syncthreads();
        #pragma unroll
        for (int kk = 0; kk < 16; ++kk) {
            float4 a4 = *(const float4*)&As[kk][tx * 4];
            float4 b4 = *(const float4*)&Bs[kk][ty * 4];
            float a[4] = {a4.x, a4.y, a4.z, a4.w};
            float bb[4] = {b4.x, b4.y, b4.z, b4.w};
            #pragma unroll
            for (int i = 0; i < 4; ++i)
                #pragma unroll
                for (int j = 0; j < 4; ++j) acc[i][j] += a[i] * bb[j];
        }
    }
    const float scale = 0.044194173824159216f;  // 1/sqrt(512)
    #pragma unroll
    for (int i = 0; i < 4; ++i) {
        int t = m0 + tx * 4 + i;
        size_t rowbase = ((size_t)b * TGT + t) * APITCH;
        #pragma unroll
        for (int j = 0; j < 4; ++j) {
            int s = n0 + ty * 4 + j;
            if (s < SALL) atten[rowbase + s] = acc[i][j] * scale;
        }
    }
}

// ---------------- finalize: per (b,t) row ----------------
__global__ __launch_bounds__(256) void finalize(
    const float* __restrict__ atten, const int* __restrict__ ce,
    const float* __restrict__ out_logits, float* __restrict__ out)
{
    __shared__ float p[VOC];
    __shared__ float red[4];
    const int bt = blockIdx.x;
    const int b = bt >> 8;
    const int tid = threadIdx.x;
    const float* arow = atten + (size_t)bt * APITCH;
    const int* cerow = ce + (size_t)b * SRC;
    const float NEG = -1000000000.0f;
    const float EPSF = 1.1920929e-07f;
    const float FMINV = -3.4028234663852886e+38f;

    // masked log-softmax over s=0..2048
    float mx = -INFINITY;
    for (int s = tid; s < SALL; s += 256) {
        float v = arow[s];
        if (s < SRC && cerow[s] == 0) v = NEG;
        mx = fmaxf(mx, v);
    }
    mx = blockReduceMax(mx, red);
    float sm = 0.f;
    for (int s = tid; s < SALL; s += 256) {
        float v = arow[s];
        if (s < SRC && cerow[s] == 0) v = NEG;
        sm += expf(v - mx);
    }
    sm = blockReduceSum(sm, red);
    const float logZ = mx + logf(sm);
    const float g = arow[SRC] - logZ;   // gate (sentinel, never masked)

    // scatter exp(atten) into p by content id
    for (int v = tid; v < VOC; v += 256) p[v] = 0.f;
    __syncthreads();
    for (int s = tid; s < SRC; s += 256) {
        int idx = cerow[s];
        if (idx == 0) continue;                   // masked -> exp ~ 0 into p[0]
        atomicAdd(&p[idx], expf(arow[s] - logZ));
    }
    __syncthreads();

    // log-softmax denom of out_logits row
    const float* lrow = out_logits + (size_t)bt * TV;
    float mo = -INFINITY;
    for (int v = tid; v < TV; v += 256) mo = fmaxf(mo, lrow[v]);
    mo = blockReduceMax(mo, red);
    float so = 0.f;
    for (int v = tid; v < TV; v += 256) so += expf(lrow[v] - mo);
    so = blockReduceSum(so, red);
    const float logZo = mo + logf(so);

    // final combine
    const float eg = expf(g);
    const float lg1p = log1pf(-eg + EPSF);
    const float lg = logf(1.0f - eg + EPSF);
    float* orow = out + (size_t)bt * VOC;
    for (int v = tid; v < VOC; v += 256) {
        float pal = logf(p[v] + EPSF) - lg1p;
        if (isinf(pal) && pal < 0.f) pal = FMINV;
        float a = (v < TV) ? (lrow[v] - logZo + g) : -INFINITY;
        float b2 = pal + lg;
        float m2 = fmaxf(a, b2);
        orow[v] = m2 + logf(expf(a - m2) + expf(b2 - m2));
    }
}

extern "C" void kernel_launch(void* const* d_in, const int* in_sizes, int n_in,
                              void* d_out, int out_size, void* d_ws, size_t ws_size,
                              hipStream_t stream) {
    const float* out_logits = (const float*)d_in[0];
    const float* feature    = (const float*)d_in[1];
    const float* memory_raw = (const float*)d_in[2];
    const int*   content_e  = (const int*)d_in[3];
    const float* Wq = (const float*)d_in[4];
    const float* bq = (const float*)d_in[5];
    const float* Wk = (const float*)d_in[6];
    const float* bk = (const float*)d_in[7];
    const float* sentinel = (const float*)d_in[8];
    float* out = (float*)d_out;

    float* keys  = (float*)d_ws;                        // 16*2049*512 f32
    float* query = keys + (size_t)BSZ * SALL * HID;     // 16*256*512 f32
    float* atten = query + (size_t)BSZ * TGT * HID;     // 16*256*2064 f32

    hipLaunchKernelGGL(gemm_keys, dim3(1024 / 64, (BSZ * LSEQ) / 64), dim3(256), 0, stream,
                       memory_raw, Wk, bk, keys);
    hipLaunchKernelGGL(fill_sentinel, dim3(BSZ), dim3(256), 0, stream, sentinel, keys);
    hipLaunchKernelGGL(gemm_query, dim3(HID / 64, (BSZ * TGT) / 64), dim3(256), 0, stream,
                       feature, Wq, bq, query);
    hipLaunchKernelGGL(gemm_atten, dim3((SALL + 63) / 64, TGT / 64, BSZ), dim3(256), 0, stream,
                       query, keys, atten);
    hipLaunchKernelGGL(finalize, dim3(BSZ * TGT), dim3(256), 0, stream,
                       atten, content_e, out_logits, out);
}

// Round 2
// 184.657 us; speedup vs baseline: 2.6410x; 2.6410x over previous
//
#include <hip/hip_runtime.h>
#include <math.h>

#define BSZ   16
#define LSEQ  1024
#define TGT   256
#define HID   512
#define TV    2000
#define VOC   3000
#define SRC   2048
#define SALL  2049
#define KPAD  2176    // keys rows per batch, padded to multiple of 128
#define APITCH 2064   // padded atten row pitch (float4-aligned)

typedef unsigned short u16;
typedef __attribute__((ext_vector_type(8))) short bf16x8;
typedef __attribute__((ext_vector_type(4))) float f32x4;

__device__ __forceinline__ u16 f2bf(float x) {
    unsigned u = __float_as_uint(x);
    u += 0x7FFFu + ((u >> 16) & 1u);
    return (u16)(u >> 16);
}

static __device__ __forceinline__ float gelu_exact(float x) {
    return 0.5f * x * (1.0f + erff(x * 0.70710678118654752f));
}

// ---------------- block reductions (256 threads = 4 waves) ----------------
__device__ __forceinline__ float blockReduceMax(float v, float* red) {
    #pragma unroll
    for (int o = 32; o > 0; o >>= 1) v = fmaxf(v, __shfl_down(v, o, 64));
    const int wid = threadIdx.x >> 6, lane = threadIdx.x & 63;
    __syncthreads();
    if (lane == 0) red[wid] = v;
    __syncthreads();
    return fmaxf(fmaxf(red[0], red[1]), fmaxf(red[2], red[3]));
}
__device__ __forceinline__ float blockReduceSum(float v, float* red) {
    #pragma unroll
    for (int o = 32; o > 0; o >>= 1) v += __shfl_down(v, o, 64);
    const int wid = threadIdx.x >> 6, lane = threadIdx.x & 63;
    __syncthreads();
    if (lane == 0) red[wid] = v;
    __syncthreads();
    return red[0] + red[1] + red[2] + red[3];
}

// ---------------- cast fp32 -> bf16 (vectorized, 8 elems/thread) ----------------
__global__ __launch_bounds__(256) void cast_bf16(
    const float4* __restrict__ in, int4* __restrict__ out, int n8)
{
    int i = blockIdx.x * 256 + threadIdx.x;
    if (i >= n8) return;
    float4 x = in[2 * i], y = in[2 * i + 1];
    unsigned p0 = (unsigned)f2bf(x.x) | ((unsigned)f2bf(x.y) << 16);
    unsigned p1 = (unsigned)f2bf(x.z) | ((unsigned)f2bf(x.w) << 16);
    unsigned p2 = (unsigned)f2bf(y.x) | ((unsigned)f2bf(y.y) << 16);
    unsigned p3 = (unsigned)f2bf(y.z) | ((unsigned)f2bf(y.w) << 16);
    out[i] = make_int4(p0, p1, p2, p3);
}

// ---------------- transpose + cast: in fp32 [rows][cols] -> out bf16 [cols][rows] ----------------
__global__ __launch_bounds__(256) void transpose_cast(
    const float* __restrict__ in, u16* __restrict__ out, int rows, int cols)
{
    __shared__ float t[32][33];
    const int bx = blockIdx.x * 32, by = blockIdx.y * 32;
    const int tx = threadIdx.x & 31, ty = threadIdx.x >> 5;
    #pragma unroll
    for (int k = 0; k < 4; ++k)
        t[ty + 8 * k][tx] = in[(size_t)(by + ty + 8 * k) * cols + bx + tx];
    __syncthreads();
    #pragma unroll
    for (int k = 0; k < 4; ++k)
        out[(size_t)(bx + ty + 8 * k) * rows + by + tx] = f2bf(t[tx][ty + 8 * k]);
}

// ---------------- sentinel row + zero pad rows of keys ----------------
__global__ __launch_bounds__(256) void fill_tail(
    const float* __restrict__ sent, u16* __restrict__ keys)
{
    const int b = blockIdx.x;
    u16* kb = keys + (size_t)b * KPAD * HID;
    for (int h = threadIdx.x; h < HID; h += 256)
        kb[(size_t)SRC * HID + h] = f2bf(sent[h]);
    int4* z = (int4*)(kb + (size_t)SALL * HID);
    const int nz = (KPAD - SALL) * HID / 8;   // 127*512/8
    for (int i = threadIdx.x; i < nz; i += 256) z[i] = make_int4(0, 0, 0, 0);
}

// ---------------- MFMA GEMM: C[M,N] = A[M,K=512] . B^T[N,K=512], 128x128 tile ----------------
// EPI 0: keys epilogue (+bias, reshape to [b][s][h] bf16)
// EPI 1: query epilogue (+bias, gelu, bf16)
// EPI 2: atten epilogue (scale, fp32, batched via blockIdx.z)
template<int EPI>
__global__ __launch_bounds__(256) void gemm_mfma(
    const u16* __restrict__ Abase, const u16* __restrict__ Bbase,
    const float* __restrict__ bias, float* __restrict__ outf, u16* __restrict__ outb)
{
    __shared__ u16 As[128 * 40];
    __shared__ u16 Bs[128 * 40];
    const int tid = threadIdx.x;
    const int lane = tid & 63;
    const int w = tid >> 6;
    const int wr = (w >> 1) * 64, wc = (w & 1) * 64;
    const int m0 = blockIdx.y * 128, n0 = blockIdx.x * 128;

    const u16* Ag;
    const u16* Bg;
    if (EPI == 2) {
        Ag = Abase + (size_t)blockIdx.z * TGT * HID;
        Bg = Bbase + (size_t)blockIdx.z * KPAD * HID;
    } else {
        Ag = Abase;
        Bg = Bbase;
    }

    const int srow = tid >> 2;
    const int scol = (tid & 3) * 8;
    const u16* Ag0 = Ag + (size_t)(m0 + srow) * HID + scol;
    const u16* Bg0 = Bg + (size_t)(n0 + srow) * HID + scol;
    u16* wa0 = As + srow * 40 + scol;
    u16* wa1 = As + (srow + 64) * 40 + scol;
    u16* wb0 = Bs + srow * 40 + scol;
    u16* wb1 = Bs + (srow + 64) * 40 + scol;

    const int la = lane & 15, lb = lane >> 4;
    f32x4 acc[4][4] = {};

    for (int k0 = 0; k0 < HID; k0 += 32) {
        int4 a0 = *(const int4*)(Ag0 + k0);
        int4 a1 = *(const int4*)(Ag0 + (size_t)64 * HID + k0);
        int4 b0 = *(const int4*)(Bg0 + k0);
        int4 b1 = *(const int4*)(Bg0 + (size_t)64 * HID + k0);
        __syncthreads();
        *(int4*)wa0 = a0;
        *(int4*)wa1 = a1;
        *(int4*)wb0 = b0;
        *(int4*)wb1 = b1;
        __syncthreads();
        bf16x8 af[4], bfv[4];
        #pragma unroll
        for (int i = 0; i < 4; ++i)
            af[i] = *(const bf16x8*)(As + (wr + i * 16 + la) * 40 + lb * 8);
        #pragma unroll
        for (int j = 0; j < 4; ++j)
            bfv[j] = *(const bf16x8*)(Bs + (wc + j * 16 + la) * 40 + lb * 8);
        #pragma unroll
        for (int i = 0; i < 4; ++i)
            #pragma unroll
            for (int j = 0; j < 4; ++j)
                acc[i][j] = __builtin_amdgcn_mfma_f32_16x16x32_bf16(af[i], bfv[j], acc[i][j], 0, 0, 0);
    }

    // C/D layout (m89-verified): col = lane&15 (n), row = (lane>>4)*4 + reg (m)
    const int r_l = (lane >> 4) * 4, c_l = lane & 15;
    if (EPI == 0) {
        #pragma unroll
        for (int j = 0; j < 4; ++j) {
            const int n = n0 + wc + j * 16 + c_l;
            const float bv = bias[n];
            #pragma unroll
            for (int i = 0; i < 4; ++i)
                #pragma unroll
                for (int r = 0; r < 4; ++r) {
                    const int m = m0 + wr + i * 16 + r_l + r;
                    const int b = m >> 10, l = m & 1023;
                    const int s = 2 * l + (n >> 9), h = n & 511;
                    outb[((size_t)b * KPAD + s) * HID + h] = f2bf(acc[i][j][r] + bv);
                }
        }
    } else if (EPI == 1) {
        #pragma unroll
        for (int j = 0; j < 4; ++j) {
            const int n = n0 + wc + j * 16 + c_l;
            const float bv = bias[n];
            #pragma unroll
            for (int i = 0; i < 4; ++i)
                #pragma unroll
                for (int r = 0; r < 4; ++r) {
                    const int m = m0 + wr + i * 16 + r_l + r;
                    outb[(size_t)m * HID + n] = f2bf(gelu_exact(acc[i][j][r] + bv));
                }
        }
    } else {
        const float scale = 0.044194173824159216f;  // 1/sqrt(512)
        #pragma unroll
        for (int j = 0; j < 4; ++j) {
            const int s = n0 + wc + j * 16 + c_l;
            if (s < SALL) {
                #pragma unroll
                for (int i = 0; i < 4; ++i)
                    #pragma unroll
                    for (int r = 0; r < 4; ++r) {
                        const int t = m0 + wr + i * 16 + r_l + r;
                        outf[((size_t)(blockIdx.z * TGT + t)) * APITCH + s] = acc[i][j][r] * scale;
                    }
            }
        }
    }
}

// ---------------- finalize: per (b,t) row ----------------
__global__ __launch_bounds__(256) void finalize(
    const float* __restrict__ atten, const int* __restrict__ ce,
    const float* __restrict__ out_logits, float* __restrict__ out)
{
    __shared__ float ev[SALL];   // masked row, then exp(v - mx)
    __shared__ float lg[TV];     // out_logits row cache
    __shared__ float p[VOC];
    __shared__ float red[4];
    const int bt = blockIdx.x;
    const int b = bt >> 8;
    const int tid = threadIdx.x;
    const float* arow = atten + (size_t)bt * APITCH;
    const int* cerow = ce + (size_t)b * SRC;
    const float NEG = -1000000000.0f;
    const float EPSF = 1.1920929e-07f;
    const float FMINV = -3.4028234663852886e+38f;

    // pass 1: load + mask + max
    float mx = -INFINITY;
    for (int s = tid; s < SALL; s += 256) {
        float v = arow[s];
        if (s < SRC && cerow[s] == 0) v = NEG;
        ev[s] = v;
        mx = fmaxf(mx, v);
    }
    mx = blockReduceMax(mx, red);
    // pass 2: exp + sum (from LDS)
    float sm = 0.f;
    for (int s = tid; s < SALL; s += 256) {
        float e = __expf(ev[s] - mx);
        ev[s] = e;
        sm += e;
    }
    sm = blockReduceSum(sm, red);
    const float inv = 1.0f / sm;
    const float eg = ev[SRC] * inv;        // gate probability
    const float g = __logf(eg);            // log gate

    // scatter probabilities into p
    for (int v = tid; v < VOC; v += 256) p[v] = 0.f;
    __syncthreads();
    for (int s = tid; s < SRC; s += 256) {
        int idx = cerow[s];
        if (idx == 0) continue;
        atomicAdd(&p[idx], ev[s] * inv);
    }
    __syncthreads();

    // out_logits log-softmax denominator (row cached in LDS)
    const float* lrow = out_logits + (size_t)bt * TV;
    float mo = -INFINITY;
    for (int v = tid; v < TV; v += 256) {
        float f = lrow[v];
        lg[v] = f;
        mo = fmaxf(mo, f);
    }
    mo = blockReduceMax(mo, red);
    float so = 0.f;
    for (int v = tid; v < TV; v += 256) so += __expf(lg[v] - mo);
    so = blockReduceSum(so, red);
    const float logZo = mo + __logf(so);

    // final combine
    const float lg1p = log1pf(-eg + EPSF);
    const float lgm = __logf(1.0f - eg + EPSF);
    float* orow = out + (size_t)bt * VOC;
    for (int v = tid; v < VOC; v += 256) {
        float pal = __logf(p[v] + EPSF) - lg1p;
        if (isinf(pal) && pal < 0.f) pal = FMINV;
        float b2 = pal + lgm;
        float o;
        if (v < TV) {
            float a = lg[v] - logZo + g;
            float m2 = fmaxf(a, b2);
            o = m2 + __logf(__expf(a - m2) + __expf(b2 - m2));
        } else {
            o = b2;
        }
        orow[v] = o;
    }
}

extern "C" void kernel_launch(void* const* d_in, const int* in_sizes, int n_in,
                              void* d_out, int out_size, void* d_ws, size_t ws_size,
                              hipStream_t stream) {
    const float* out_logits = (const float*)d_in[0];
    const float* feature    = (const float*)d_in[1];
    const float* memory_raw = (const float*)d_in[2];
    const int*   content_e  = (const int*)d_in[3];
    const float* Wq = (const float*)d_in[4];
    const float* bq = (const float*)d_in[5];
    const float* Wk = (const float*)d_in[6];
    const float* bk = (const float*)d_in[7];
    const float* sentinel = (const float*)d_in[8];
    float* out = (float*)d_out;

    u16* a_mem  = (u16*)d_ws;                            // 16384*512
    u16* feat   = a_mem  + (size_t)16384 * 512;          // 4096*512
    u16* wkT    = feat   + (size_t)4096 * 512;           // 1024*512
    u16* wqT    = wkT    + (size_t)1024 * 512;           // 512*512
    u16* keysb  = wqT    + (size_t)512 * 512;            // 16*KPAD*512
    u16* queryb = keysb  + (size_t)BSZ * KPAD * HID;     // 4096*512
    float* atten = (float*)(queryb + (size_t)4096 * 512); // 16*256*APITCH f32

    // casts
    cast_bf16<<<(16384 * 512 / 8) / 256, 256, 0, stream>>>(
        (const float4*)memory_raw, (int4*)a_mem, 16384 * 512 / 8);
    cast_bf16<<<(4096 * 512 / 8) / 256, 256, 0, stream>>>(
        (const float4*)feature, (int4*)feat, 4096 * 512 / 8);
    transpose_cast<<<dim3(1024 / 32, 512 / 32), 256, 0, stream>>>(Wk, wkT, 512, 1024);
    transpose_cast<<<dim3(512 / 32, 512 / 32), 256, 0, stream>>>(Wq, wqT, 512, 512);

    // GEMMs
    gemm_mfma<0><<<dim3(1024 / 128, 16384 / 128), 256, 0, stream>>>(
        a_mem, wkT, bk, nullptr, keysb);
    fill_tail<<<BSZ, 256, 0, stream>>>(sentinel, keysb);
    gemm_mfma<1><<<dim3(512 / 128, 4096 / 128), 256, 0, stream>>>(
        feat, wqT, bq, nullptr, queryb);
    gemm_mfma<2><<<dim3(17, TGT / 128, BSZ), 256, 0, stream>>>(
        queryb, keysb, nullptr, atten, nullptr);

    finalize<<<BSZ * TGT, 256, 0, stream>>>(atten, content_e, out_logits, out);
}

// Round 3
// 168.029 us; speedup vs baseline: 2.9024x; 1.0990x over previous
//
#include <hip/hip_runtime.h>
#include <math.h>

#define BSZ   16
#define LSEQ  1024
#define TGT   256
#define HID   512
#define TV    2000
#define VOC   3000
#define SRC   2048
#define SALL  2049
#define KPAD  2176    // keys rows per batch, padded to multiple of 128
#define APITCH 2064   // padded atten row pitch (float4-aligned)

typedef unsigned short u16;
typedef __attribute__((ext_vector_type(8))) short bf16x8;
typedef __attribute__((ext_vector_type(4))) float f32x4;

__device__ __forceinline__ u16 f2bf(float x) {
    unsigned u = __float_as_uint(x);
    u += 0x7FFFu + ((u >> 16) & 1u);
    return (u16)(u >> 16);
}

static __device__ __forceinline__ float gelu_exact(float x) {
    return 0.5f * x * (1.0f + erff(x * 0.70710678118654752f));
}

// ---------------- block reductions (256 threads = 4 waves) ----------------
__device__ __forceinline__ float blockReduceMax(float v, float* red) {
    #pragma unroll
    for (int o = 32; o > 0; o >>= 1) v = fmaxf(v, __shfl_down(v, o, 64));
    const int wid = threadIdx.x >> 6, lane = threadIdx.x & 63;
    __syncthreads();
    if (lane == 0) red[wid] = v;
    __syncthreads();
    return fmaxf(fmaxf(red[0], red[1]), fmaxf(red[2], red[3]));
}
__device__ __forceinline__ float blockReduceSum(float v, float* red) {
    #pragma unroll
    for (int o = 32; o > 0; o >>= 1) v += __shfl_down(v, o, 64);
    const int wid = threadIdx.x >> 6, lane = threadIdx.x & 63;
    __syncthreads();
    if (lane == 0) red[wid] = v;
    __syncthreads();
    return red[0] + red[1] + red[2] + red[3];
}

// ---------------- cast fp32 -> bf16 (vectorized, 8 elems/thread) ----------------
__global__ __launch_bounds__(256) void cast_bf16(
    const float4* __restrict__ in, int4* __restrict__ out, int n8)
{
    int i = blockIdx.x * 256 + threadIdx.x;
    if (i >= n8) return;
    float4 x = in[2 * i], y = in[2 * i + 1];
    unsigned p0 = (unsigned)f2bf(x.x) | ((unsigned)f2bf(x.y) << 16);
    unsigned p1 = (unsigned)f2bf(x.z) | ((unsigned)f2bf(x.w) << 16);
    unsigned p2 = (unsigned)f2bf(y.x) | ((unsigned)f2bf(y.y) << 16);
    unsigned p3 = (unsigned)f2bf(y.z) | ((unsigned)f2bf(y.w) << 16);
    out[i] = make_int4(p0, p1, p2, p3);
}

// ---------------- transpose + cast: in fp32 [rows][cols] -> out bf16 [cols][rows] ----------------
__global__ __launch_bounds__(256) void transpose_cast(
    const float* __restrict__ in, u16* __restrict__ out, int rows, int cols)
{
    __shared__ float t[32][33];
    const int bx = blockIdx.x * 32, by = blockIdx.y * 32;
    const int tx = threadIdx.x & 31, ty = threadIdx.x >> 5;
    #pragma unroll
    for (int k = 0; k < 4; ++k)
        t[ty + 8 * k][tx] = in[(size_t)(by + ty + 8 * k) * cols + bx + tx];
    __syncthreads();
    #pragma unroll
    for (int k = 0; k < 4; ++k)
        out[(size_t)(bx + ty + 8 * k) * rows + by + tx] = f2bf(t[tx][ty + 8 * k]);
}

// ---------------- sentinel row + zero pad rows of keys ----------------
__global__ __launch_bounds__(256) void fill_tail(
    const float* __restrict__ sent, u16* __restrict__ keys)
{
    const int b = blockIdx.x;
    u16* kb = keys + (size_t)b * KPAD * HID;
    for (int h = threadIdx.x; h < HID; h += 256)
        kb[(size_t)SRC * HID + h] = f2bf(sent[h]);
    int4* z = (int4*)(kb + (size_t)SALL * HID);
    const int nz = (KPAD - SALL) * HID / 8;   // 127*512/8
    for (int i = threadIdx.x; i < nz; i += 256) z[i] = make_int4(0, 0, 0, 0);
}

// ---------------- MFMA GEMM: C[M,N] = A[M,K=512] . B^T[N,K=512], 128x128 tile ----------------
template<int EPI>
__global__ __launch_bounds__(256) void gemm_mfma(
    const u16* __restrict__ Abase, const u16* __restrict__ Bbase,
    const float* __restrict__ bias, float* __restrict__ outf, u16* __restrict__ outb)
{
    __shared__ u16 As[128 * 40];
    __shared__ u16 Bs[128 * 40];
    const int tid = threadIdx.x;
    const int lane = tid & 63;
    const int w = tid >> 6;
    const int wr = (w >> 1) * 64, wc = (w & 1) * 64;
    const int m0 = blockIdx.y * 128, n0 = blockIdx.x * 128;

    const u16* Ag;
    const u16* Bg;
    if (EPI == 2) {
        Ag = Abase + (size_t)blockIdx.z * TGT * HID;
        Bg = Bbase + (size_t)blockIdx.z * KPAD * HID;
    } else {
        Ag = Abase;
        Bg = Bbase;
    }

    const int srow = tid >> 2;
    const int scol = (tid & 3) * 8;
    const u16* Ag0 = Ag + (size_t)(m0 + srow) * HID + scol;
    const u16* Bg0 = Bg + (size_t)(n0 + srow) * HID + scol;
    u16* wa0 = As + srow * 40 + scol;
    u16* wa1 = As + (srow + 64) * 40 + scol;
    u16* wb0 = Bs + srow * 40 + scol;
    u16* wb1 = Bs + (srow + 64) * 40 + scol;

    const int la = lane & 15, lb = lane >> 4;
    f32x4 acc[4][4] = {};

    for (int k0 = 0; k0 < HID; k0 += 32) {
        int4 a0 = *(const int4*)(Ag0 + k0);
        int4 a1 = *(const int4*)(Ag0 + (size_t)64 * HID + k0);
        int4 b0 = *(const int4*)(Bg0 + k0);
        int4 b1 = *(const int4*)(Bg0 + (size_t)64 * HID + k0);
        __syncthreads();
        *(int4*)wa0 = a0;
        *(int4*)wa1 = a1;
        *(int4*)wb0 = b0;
        *(int4*)wb1 = b1;
        __syncthreads();
        bf16x8 af[4], bfv[4];
        #pragma unroll
        for (int i = 0; i < 4; ++i)
            af[i] = *(const bf16x8*)(As + (wr + i * 16 + la) * 40 + lb * 8);
        #pragma unroll
        for (int j = 0; j < 4; ++j)
            bfv[j] = *(const bf16x8*)(Bs + (wc + j * 16 + la) * 40 + lb * 8);
        #pragma unroll
        for (int i = 0; i < 4; ++i)
            #pragma unroll
            for (int j = 0; j < 4; ++j)
                acc[i][j] = __builtin_amdgcn_mfma_f32_16x16x32_bf16(af[i], bfv[j], acc[i][j], 0, 0, 0);
    }

    const int r_l = (lane >> 4) * 4, c_l = lane & 15;
    if (EPI == 0) {
        #pragma unroll
        for (int j = 0; j < 4; ++j) {
            const int n = n0 + wc + j * 16 + c_l;
            const float bv = bias[n];
            #pragma unroll
            for (int i = 0; i < 4; ++i)
                #pragma unroll
                for (int r = 0; r < 4; ++r) {
                    const int m = m0 + wr + i * 16 + r_l + r;
                    const int b = m >> 10, l = m & 1023;
                    const int s = 2 * l + (n >> 9), h = n & 511;
                    outb[((size_t)b * KPAD + s) * HID + h] = f2bf(acc[i][j][r] + bv);
                }
        }
    } else if (EPI == 1) {
        #pragma unroll
        for (int j = 0; j < 4; ++j) {
            const int n = n0 + wc + j * 16 + c_l;
            const float bv = bias[n];
            #pragma unroll
            for (int i = 0; i < 4; ++i)
                #pragma unroll
                for (int r = 0; r < 4; ++r) {
                    const int m = m0 + wr + i * 16 + r_l + r;
                    outb[(size_t)m * HID + n] = f2bf(gelu_exact(acc[i][j][r] + bv));
                }
        }
    } else {
        const float scale = 0.044194173824159216f;  // 1/sqrt(512)
        #pragma unroll
        for (int j = 0; j < 4; ++j) {
            const int s = n0 + wc + j * 16 + c_l;
            if (s < SALL) {
                #pragma unroll
                for (int i = 0; i < 4; ++i)
                    #pragma unroll
                    for (int r = 0; r < 4; ++r) {
                        const int t = m0 + wr + i * 16 + r_l + r;
                        outf[((size_t)(blockIdx.z * TGT + t)) * APITCH + s] = acc[i][j][r] * scale;
                    }
            }
        }
    }
}

// ---------------- k_logz: logsumexp of each out_logits row (one wave per row) ----------------
__global__ __launch_bounds__(256) void k_logz(
    const float* __restrict__ logits, float* __restrict__ logZo)
{
    const int row = blockIdx.x * 4 + (threadIdx.x >> 6);
    const int lane = threadIdx.x & 63;
    const float* lrow = logits + (size_t)row * TV;
    float v[31];
    float m = -INFINITY;
    #pragma unroll
    for (int i = 0; i < 31; ++i) {          // 31*64 = 1984
        v[i] = lrow[lane + i * 64];
        m = fmaxf(m, v[i]);
    }
    float vt = (lane < 16) ? lrow[1984 + lane] : -INFINITY;   // tail 16
    m = fmaxf(m, vt);
    #pragma unroll
    for (int o = 32; o > 0; o >>= 1) m = fmaxf(m, __shfl_xor(m, o, 64));
    float s = (lane < 16) ? __expf(vt - m) : 0.f;
    #pragma unroll
    for (int i = 0; i < 31; ++i) s += __expf(v[i] - m);
    #pragma unroll
    for (int o = 32; o > 0; o >>= 1) s += __shfl_xor(s, o, 64);
    if (lane == 0) logZo[row] = m + __logf(s);
}

// ---------------- finalize: per (b,t) row, register-resident ----------------
__global__ __launch_bounds__(256) void finalize(
    const float* __restrict__ atten, const int* __restrict__ ce,
    const float* __restrict__ out_logits, const float* __restrict__ logZo,
    float* __restrict__ out)
{
    __shared__ float p[VOC];
    __shared__ float red[4];
    const int bt = blockIdx.x;
    const int b = bt >> 8;
    const int tid = threadIdx.x;
    const float* arow = atten + (size_t)bt * APITCH;
    const int* cerow = ce + (size_t)b * SRC;
    const float NEG = -1000000000.0f;
    const float EPSF = 1.1920929e-07f;
    const float FMINV = -3.4028234663852886e+38f;

    // init p (barrier provided by first blockReduce)
    for (int v = tid; v < VOC; v += 256) p[v] = 0.f;

    // register-resident load of this thread's 8 slots (SRC = 8*256 exactly)
    const float sent_v = arow[SRC];
    float v[8];
    int ci[8];
    float mx = sent_v;
    #pragma unroll
    for (int i = 0; i < 8; ++i) {
        const int s = tid + 256 * i;
        ci[i] = cerow[s];
        float x = arow[s];
        if (ci[i] == 0) x = NEG;
        v[i] = x;
        mx = fmaxf(mx, x);
    }
    mx = blockReduceMax(mx, red);

    float e[8];
    float sm = 0.f;
    #pragma unroll
    for (int i = 0; i < 8; ++i) {
        e[i] = __expf(v[i] - mx);
        sm += e[i];
    }
    if (tid == 0) sm += __expf(sent_v - mx);
    sm = blockReduceSum(sm, red);

    const float inv = 1.0f / sm;
    const float g = sent_v - (mx + __logf(sm));   // log gate
    const float eg = __expf(g);

    #pragma unroll
    for (int i = 0; i < 8; ++i)
        if (ci[i] != 0) atomicAdd(&p[ci[i]], e[i] * inv);
    __syncthreads();

    // final combine
    const float lZo = logZo[bt];
    const float lg1p = log1pf(-eg + EPSF);
    const float lgm = __logf(1.0f - eg + EPSF);
    const float* lrow = out_logits + (size_t)bt * TV;
    float* orow = out + (size_t)bt * VOC;
    for (int vv = tid; vv < VOC; vv += 256) {
        float pal = __logf(p[vv] + EPSF) - lg1p;
        if (isinf(pal) && pal < 0.f) pal = FMINV;
        float b2 = pal + lgm;
        float o;
        if (vv < TV) {
            float a = lrow[vv] - lZo + g;
            float m2 = fmaxf(a, b2);
            o = m2 + __logf(__expf(a - m2) + __expf(b2 - m2));
        } else {
            o = b2;
        }
        orow[vv] = o;
    }
}

extern "C" void kernel_launch(void* const* d_in, const int* in_sizes, int n_in,
                              void* d_out, int out_size, void* d_ws, size_t ws_size,
                              hipStream_t stream) {
    const float* out_logits = (const float*)d_in[0];
    const float* feature    = (const float*)d_in[1];
    const float* memory_raw = (const float*)d_in[2];
    const int*   content_e  = (const int*)d_in[3];
    const float* Wq = (const float*)d_in[4];
    const float* bq = (const float*)d_in[5];
    const float* Wk = (const float*)d_in[6];
    const float* bk = (const float*)d_in[7];
    const float* sentinel = (const float*)d_in[8];
    float* out = (float*)d_out;

    u16* a_mem  = (u16*)d_ws;                            // 16384*512
    u16* feat   = a_mem  + (size_t)16384 * 512;          // 4096*512
    u16* wkT    = feat   + (size_t)4096 * 512;           // 1024*512
    u16* wqT    = wkT    + (size_t)1024 * 512;           // 512*512
    u16* keysb  = wqT    + (size_t)512 * 512;            // 16*KPAD*512
    u16* queryb = keysb  + (size_t)BSZ * KPAD * HID;     // 4096*512
    float* atten = (float*)(queryb + (size_t)4096 * 512); // 16*256*APITCH f32
    float* logZo = atten + (size_t)BSZ * TGT * APITCH;   // 4096 f32

    // independent of GEMM chain — run first
    k_logz<<<BSZ * TGT / 4, 256, 0, stream>>>(out_logits, logZo);

    // casts
    cast_bf16<<<(16384 * 512 / 8) / 256, 256, 0, stream>>>(
        (const float4*)memory_raw, (int4*)a_mem, 16384 * 512 / 8);
    cast_bf16<<<(4096 * 512 / 8) / 256, 256, 0, stream>>>(
        (const float4*)feature, (int4*)feat, 4096 * 512 / 8);
    transpose_cast<<<dim3(1024 / 32, 512 / 32), 256, 0, stream>>>(Wk, wkT, 512, 1024);
    transpose_cast<<<dim3(512 / 32, 512 / 32), 256, 0, stream>>>(Wq, wqT, 512, 512);

    // GEMMs
    gemm_mfma<0><<<dim3(1024 / 128, 16384 / 128), 256, 0, stream>>>(
        a_mem, wkT, bk, nullptr, keysb);
    fill_tail<<<BSZ, 256, 0, stream>>>(sentinel, keysb);
    gemm_mfma<1><<<dim3(512 / 128, 4096 / 128), 256, 0, stream>>>(
        feat, wqT, bq, nullptr, queryb);
    gemm_mfma<2><<<dim3(17, TGT / 128, BSZ), 256, 0, stream>>>(
        queryb, keysb, nullptr, atten, nullptr);

    finalize<<<BSZ * TGT, 256, 0, stream>>>(atten, content_e, out_logits, logZo, out);
}

// Round 4
// 141.985 us; speedup vs baseline: 3.4348x; 1.1834x over previous
//
#include <hip/hip_runtime.h>
#include <math.h>

#define BSZ   16
#define LSEQ  1024
#define TGT   256
#define HID   512
#define TV    2000
#define VOC   3000
#define SRC   2048
#define SALL  2049
#define KPAD  2176    // keys rows per batch, padded to multiple of 128
#define APITCH 2064   // padded atten row pitch (float4-aligned)

typedef unsigned short u16;
typedef __attribute__((ext_vector_type(8))) short bf16x8;
typedef __attribute__((ext_vector_type(4))) float f32x4;

__device__ __forceinline__ u16 f2bf(float x) {
    unsigned u = __float_as_uint(x);
    u += 0x7FFFu + ((u >> 16) & 1u);
    return (u16)(u >> 16);
}

static __device__ __forceinline__ float gelu_exact(float x) {
    return 0.5f * x * (1.0f + erff(x * 0.70710678118654752f));
}

// ---------------- PREP mega-kernel: casts + weight transposes + logits LSE ----------------
// blocks: [0,4096) cast memory_raw | [4096,5120) cast feature |
//         [5120,5632) Wk^T | [5632,5888) Wq^T | [5888,6912) k_logz
__device__ __forceinline__ void cast8_body(const float4* __restrict__ in,
                                           int4* __restrict__ out, int i) {
    float4 x = in[2 * i], y = in[2 * i + 1];
    unsigned p0 = (unsigned)f2bf(x.x) | ((unsigned)f2bf(x.y) << 16);
    unsigned p1 = (unsigned)f2bf(x.z) | ((unsigned)f2bf(x.w) << 16);
    unsigned p2 = (unsigned)f2bf(y.x) | ((unsigned)f2bf(y.y) << 16);
    unsigned p3 = (unsigned)f2bf(y.z) | ((unsigned)f2bf(y.w) << 16);
    out[i] = make_int4(p0, p1, p2, p3);
}

__global__ __launch_bounds__(256) void prep(
    const float* __restrict__ memory_raw, const float* __restrict__ feature,
    const float* __restrict__ Wk, const float* __restrict__ Wq,
    const float* __restrict__ logits,
    int4* __restrict__ a_mem, int4* __restrict__ featb,
    u16* __restrict__ wkT, u16* __restrict__ wqT, float* __restrict__ logZo)
{
    __shared__ float t[32][33];
    const int id = blockIdx.x;
    const int tid = threadIdx.x;
    if (id < 4096) {
        cast8_body((const float4*)memory_raw, a_mem, id * 256 + tid);
    } else if (id < 5120) {
        cast8_body((const float4*)feature, featb, (id - 4096) * 256 + tid);
    } else if (id < 5888) {
        // transpose_cast
        const float* in; u16* outp; int rows, cols, bx, by;
        if (id < 5632) {
            int id2 = id - 5120;
            in = Wk; outp = wkT; rows = 512; cols = 1024;
            bx = (id2 & 31) * 32; by = (id2 >> 5) * 32;
        } else {
            int id2 = id - 5632;
            in = Wq; outp = wqT; rows = 512; cols = 512;
            bx = (id2 & 15) * 32; by = (id2 >> 4) * 32;
        }
        const int tx = tid & 31, ty = tid >> 5;
        #pragma unroll
        for (int k = 0; k < 4; ++k)
            t[ty + 8 * k][tx] = in[(size_t)(by + ty + 8 * k) * cols + bx + tx];
        __syncthreads();
        #pragma unroll
        for (int k = 0; k < 4; ++k)
            outp[(size_t)(bx + ty + 8 * k) * rows + by + tx] = f2bf(t[tx][ty + 8 * k]);
    } else {
        // k_logz: 4 rows per block, one wave per row, float4 loads (TV = 500 float4)
        const int row = (id - 5888) * 4 + (tid >> 6);
        const int lane = tid & 63;
        const float4* lrow4 = (const float4*)(logits + (size_t)row * TV);
        float4 v4[8];
        float m = -INFINITY;
        #pragma unroll
        for (int i = 0; i < 8; ++i) {
            int idx = lane + 64 * i;
            if (idx < 500) {
                v4[i] = lrow4[idx];
                m = fmaxf(m, fmaxf(fmaxf(v4[i].x, v4[i].y), fmaxf(v4[i].z, v4[i].w)));
            } else {
                v4[i] = make_float4(-INFINITY, -INFINITY, -INFINITY, -INFINITY);
            }
        }
        #pragma unroll
        for (int o = 32; o > 0; o >>= 1) m = fmaxf(m, __shfl_xor(m, o, 64));
        float s = 0.f;
        #pragma unroll
        for (int i = 0; i < 8; ++i) {
            s += __expf(v4[i].x - m) + __expf(v4[i].y - m)
               + __expf(v4[i].z - m) + __expf(v4[i].w - m);
        }
        #pragma unroll
        for (int o = 32; o > 0; o >>= 1) s += __shfl_xor(s, o, 64);
        if (lane == 0) logZo[row] = m + __logf(s);
    }
}

// ---------------- MFMA GEMM body: C[M,N] = A[M,K=512] . B^T[N,K=512], 128x128 tile ----------------
template<int EPI>
__device__ __forceinline__ void gemm_body(
    int m0, int n0, int z,
    const u16* __restrict__ Abase, const u16* __restrict__ Bbase,
    const float* __restrict__ bias, float* __restrict__ outf, u16* __restrict__ outb,
    u16* As, u16* Bs)
{
    const int tid = threadIdx.x;
    const int lane = tid & 63;
    const int w = tid >> 6;
    const int wr = (w >> 1) * 64, wc = (w & 1) * 64;

    const u16* Ag = Abase + (EPI == 2 ? (size_t)z * TGT * HID : 0);
    const u16* Bg = Bbase + (EPI == 2 ? (size_t)z * KPAD * HID : 0);

    const int srow = tid >> 2;
    const int scol = (tid & 3) * 8;
    const u16* Ag0 = Ag + (size_t)(m0 + srow) * HID + scol;
    const u16* Bg0 = Bg + (size_t)(n0 + srow) * HID + scol;
    u16* wa0 = As + srow * 40 + scol;
    u16* wa1 = As + (srow + 64) * 40 + scol;
    u16* wb0 = Bs + srow * 40 + scol;
    u16* wb1 = Bs + (srow + 64) * 40 + scol;

    const int la = lane & 15, lb = lane >> 4;
    f32x4 acc[4][4] = {};

    for (int k0 = 0; k0 < HID; k0 += 32) {
        int4 a0 = *(const int4*)(Ag0 + k0);
        int4 a1 = *(const int4*)(Ag0 + (size_t)64 * HID + k0);
        int4 b0 = *(const int4*)(Bg0 + k0);
        int4 b1 = *(const int4*)(Bg0 + (size_t)64 * HID + k0);
        __syncthreads();
        *(int4*)wa0 = a0;
        *(int4*)wa1 = a1;
        *(int4*)wb0 = b0;
        *(int4*)wb1 = b1;
        __syncthreads();
        bf16x8 af[4], bfv[4];
        #pragma unroll
        for (int i = 0; i < 4; ++i)
            af[i] = *(const bf16x8*)(As + (wr + i * 16 + la) * 40 + lb * 8);
        #pragma unroll
        for (int j = 0; j < 4; ++j)
            bfv[j] = *(const bf16x8*)(Bs + (wc + j * 16 + la) * 40 + lb * 8);
        #pragma unroll
        for (int i = 0; i < 4; ++i)
            #pragma unroll
            for (int j = 0; j < 4; ++j)
                acc[i][j] = __builtin_amdgcn_mfma_f32_16x16x32_bf16(af[i], bfv[j], acc[i][j], 0, 0, 0);
    }

    const int r_l = (lane >> 4) * 4, c_l = lane & 15;
    if (EPI == 0) {
        #pragma unroll
        for (int j = 0; j < 4; ++j) {
            const int n = n0 + wc + j * 16 + c_l;
            const float bv = bias[n];
            #pragma unroll
            for (int i = 0; i < 4; ++i)
                #pragma unroll
                for (int r = 0; r < 4; ++r) {
                    const int m = m0 + wr + i * 16 + r_l + r;
                    const int b = m >> 10, l = m & 1023;
                    const int s = 2 * l + (n >> 9), h = n & 511;
                    outb[((size_t)b * KPAD + s) * HID + h] = f2bf(acc[i][j][r] + bv);
                }
        }
    } else if (EPI == 1) {
        #pragma unroll
        for (int j = 0; j < 4; ++j) {
            const int n = n0 + wc + j * 16 + c_l;
            const float bv = bias[n];
            #pragma unroll
            for (int i = 0; i < 4; ++i)
                #pragma unroll
                for (int r = 0; r < 4; ++r) {
                    const int m = m0 + wr + i * 16 + r_l + r;
                    outb[(size_t)m * HID + n] = f2bf(gelu_exact(acc[i][j][r] + bv));
                }
        }
    } else {
        const float scale = 0.044194173824159216f;  // 1/sqrt(512)
        #pragma unroll
        for (int j = 0; j < 4; ++j) {
            const int s = n0 + wc + j * 16 + c_l;
            if (s < SALL) {
                #pragma unroll
                for (int i = 0; i < 4; ++i)
                    #pragma unroll
                    for (int r = 0; r < 4; ++r) {
                        const int t = m0 + wr + i * 16 + r_l + r;
                        outf[((size_t)(z * TGT + t)) * APITCH + s] = acc[i][j][r] * scale;
                    }
            }
        }
    }
}

// ---------------- merged keys-GEMM + query-GEMM + sentinel fill ----------------
// blocks: [0,1024) keys | [1024,1152) query | [1152,1168) fill_tail
__global__ __launch_bounds__(256) void gemms_a(
    const u16* __restrict__ a_mem, const u16* __restrict__ wkT, const float* __restrict__ bk,
    const u16* __restrict__ feat, const u16* __restrict__ wqT, const float* __restrict__ bq,
    const float* __restrict__ sent, u16* __restrict__ keysb, u16* __restrict__ queryb)
{
    __shared__ u16 As[128 * 40];
    __shared__ u16 Bs[128 * 40];
    const int id = blockIdx.x;
    if (id < 1024) {
        gemm_body<0>((id >> 3) * 128, (id & 7) * 128, 0, a_mem, wkT, bk, nullptr, keysb, As, Bs);
    } else if (id < 1152) {
        const int id2 = id - 1024;
        gemm_body<1>((id2 >> 2) * 128, (id2 & 3) * 128, 0, feat, wqT, bq, nullptr, queryb, As, Bs);
    } else {
        const int b = id - 1152;
        u16* kb = keysb + (size_t)b * KPAD * HID;
        for (int h = threadIdx.x; h < HID; h += 256)
            kb[(size_t)SRC * HID + h] = f2bf(sent[h]);
        int4* zp = (int4*)(kb + (size_t)SALL * HID);
        const int nz = (KPAD - SALL) * HID / 8;
        for (int i = threadIdx.x; i < nz; i += 256) zp[i] = make_int4(0, 0, 0, 0);
    }
}

// ---------------- atten GEMM ----------------
__global__ __launch_bounds__(256) void gemm_atten(
    const u16* __restrict__ Q, const u16* __restrict__ Keys, float* __restrict__ atten)
{
    __shared__ u16 As[128 * 40];
    __shared__ u16 Bs[128 * 40];
    gemm_body<2>(blockIdx.y * 128, blockIdx.x * 128, blockIdx.z,
                 Q, Keys, nullptr, atten, nullptr, As, Bs);
}

// ---------------- finalize: per (b,t) row, 128 threads, register-resident ----------------
__global__ __launch_bounds__(128, 6) void finalize(
    const float* __restrict__ atten, const int* __restrict__ ce,
    const float* __restrict__ out_logits, const float* __restrict__ logZo,
    float* __restrict__ out)
{
    __shared__ float p[VOC];
    __shared__ float red[2];
    const int bt = blockIdx.x;
    const int b = bt >> 8;
    const int tid = threadIdx.x;   // 0..127
    const float* arow = atten + (size_t)bt * APITCH;
    const float4* arow4 = (const float4*)arow;
    const int4* ce4 = (const int4*)(ce + (size_t)b * SRC);
    const float NEG = -1000000000.0f;
    const float EPSF = 1.1920929e-07f;
    const float FMINV = -3.4028234663852886e+38f;
    const int wid = tid >> 6, lane = tid & 63;

    // init p (separated from scatter by the reduce barriers)
    float4* p4 = (float4*)p;
    #pragma unroll
    for (int k = 0; k < 6; ++k) {
        int idx = tid + 128 * k;
        if (idx < 750) p4[idx] = make_float4(0.f, 0.f, 0.f, 0.f);
    }

    // register-resident load: 16 slots/thread (SRC = 16*128), float4/int4
    const float sent_v = arow[SRC];
    float v[16];
    int ci[16];
    float mx = sent_v;
    #pragma unroll
    for (int k = 0; k < 4; ++k) {
        int idx = tid + 128 * k;      // float4 index over 512
        float4 a4 = arow4[idx];
        int4 c4 = ce4[idx];
        float x0 = (c4.x == 0) ? NEG : a4.x;
        float x1 = (c4.y == 0) ? NEG : a4.y;
        float x2 = (c4.z == 0) ? NEG : a4.z;
        float x3 = (c4.w == 0) ? NEG : a4.w;
        v[4 * k + 0] = x0; v[4 * k + 1] = x1; v[4 * k + 2] = x2; v[4 * k + 3] = x3;
        ci[4 * k + 0] = c4.x; ci[4 * k + 1] = c4.y; ci[4 * k + 2] = c4.z; ci[4 * k + 3] = c4.w;
        mx = fmaxf(mx, fmaxf(fmaxf(x0, x1), fmaxf(x2, x3)));
    }
    // block reduce max (2 waves)
    #pragma unroll
    for (int o = 32; o > 0; o >>= 1) mx = fmaxf(mx, __shfl_down(mx, o, 64));
    __syncthreads();
    if (lane == 0) red[wid] = mx;
    __syncthreads();
    mx = fmaxf(red[0], red[1]);

    // exp in place + sum
    float sm = 0.f;
    #pragma unroll
    for (int i = 0; i < 16; ++i) {
        v[i] = __expf(v[i] - mx);
        sm += v[i];
    }
    if (tid == 0) sm += __expf(sent_v - mx);
    #pragma unroll
    for (int o = 32; o > 0; o >>= 1) sm += __shfl_down(sm, o, 64);
    __syncthreads();
    if (lane == 0) red[wid] = sm;
    __syncthreads();
    sm = red[0] + red[1];

    const float inv = 1.0f / sm;
    const float g = sent_v - (mx + __logf(sm));   // log gate
    const float eg = __expf(g);

    #pragma unroll
    for (int i = 0; i < 16; ++i)
        if (ci[i] != 0) atomicAdd(&p[ci[i]], v[i] * inv);
    __syncthreads();

    // final combine, float4 (TV = 500 float4, VOC = 750 float4)
    const float lZo = logZo[bt];
    const float lg1p = log1pf(-eg + EPSF);
    const float lgm = __logf(1.0f - eg + EPSF);
    const float4* lrow4 = (const float4*)(out_logits + (size_t)bt * TV);
    float4* orow4 = (float4*)(out + (size_t)bt * VOC);
    #pragma unroll
    for (int k = 0; k < 6; ++k) {
        int idx = tid + 128 * k;
        if (idx >= 750) continue;
        float4 pv = p4[idx];
        float pal0 = __logf(pv.x + EPSF) - lg1p;
        float pal1 = __logf(pv.y + EPSF) - lg1p;
        float pal2 = __logf(pv.z + EPSF) - lg1p;
        float pal3 = __logf(pv.w + EPSF) - lg1p;
        if (isinf(pal0) && pal0 < 0.f) pal0 = FMINV;
        if (isinf(pal1) && pal1 < 0.f) pal1 = FMINV;
        if (isinf(pal2) && pal2 < 0.f) pal2 = FMINV;
        if (isinf(pal3) && pal3 < 0.f) pal3 = FMINV;
        float4 o;
        if (idx < 500) {
            float4 lv = lrow4[idx];
            float a0 = lv.x - lZo + g, b0 = pal0 + lgm;
            float a1 = lv.y - lZo + g, b1 = pal1 + lgm;
            float a2 = lv.z - lZo + g, b2 = pal2 + lgm;
            float a3 = lv.w - lZo + g, b3 = pal3 + lgm;
            float m0 = fmaxf(a0, b0), m1 = fmaxf(a1, b1);
            float m2 = fmaxf(a2, b2), m3 = fmaxf(a3, b3);
            o.x = m0 + __logf(__expf(a0 - m0) + __expf(b0 - m0));
            o.y = m1 + __logf(__expf(a1 - m1) + __expf(b1 - m1));
            o.z = m2 + __logf(__expf(a2 - m2) + __expf(b2 - m2));
            o.w = m3 + __logf(__expf(a3 - m3) + __expf(b3 - m3));
        } else {
            o.x = pal0 + lgm; o.y = pal1 + lgm;
            o.z = pal2 + lgm; o.w = pal3 + lgm;
        }
        orow4[idx] = o;
    }
}

extern "C" void kernel_launch(void* const* d_in, const int* in_sizes, int n_in,
                              void* d_out, int out_size, void* d_ws, size_t ws_size,
                              hipStream_t stream) {
    const float* out_logits = (const float*)d_in[0];
    const float* feature    = (const float*)d_in[1];
    const float* memory_raw = (const float*)d_in[2];
    const int*   content_e  = (const int*)d_in[3];
    const float* Wq = (const float*)d_in[4];
    const float* bq = (const float*)d_in[5];
    const float* Wk = (const float*)d_in[6];
    const float* bk = (const float*)d_in[7];
    const float* sentinel = (const float*)d_in[8];
    float* out = (float*)d_out;

    u16* a_mem  = (u16*)d_ws;                            // 16384*512
    u16* feat   = a_mem  + (size_t)16384 * 512;          // 4096*512
    u16* wkT    = feat   + (size_t)4096 * 512;           // 1024*512
    u16* wqT    = wkT    + (size_t)1024 * 512;           // 512*512
    u16* keysb  = wqT    + (size_t)512 * 512;            // 16*KPAD*512
    u16* queryb = keysb  + (size_t)BSZ * KPAD * HID;     // 4096*512
    float* atten = (float*)(queryb + (size_t)4096 * 512); // 16*256*APITCH f32
    float* logZo = atten + (size_t)BSZ * TGT * APITCH;   // 4096 f32

    prep<<<6912, 256, 0, stream>>>(memory_raw, feature, Wk, Wq, out_logits,
                                   (int4*)a_mem, (int4*)feat, wkT, wqT, logZo);
    gemms_a<<<1168, 256, 0, stream>>>(a_mem, wkT, bk, feat, wqT, bq,
                                      sentinel, keysb, queryb);
    gemm_atten<<<dim3(17, TGT / 128, BSZ), 256, 0, stream>>>(queryb, keysb, atten);
    finalize<<<BSZ * TGT, 128, 0, stream>>>(atten, content_e, out_logits, logZo, out);
}

// Round 5
// 140.555 us; speedup vs baseline: 3.4697x; 1.0102x over previous
//
#include <hip/hip_runtime.h>
#include <math.h>

#define BSZ   16
#define LSEQ  1024
#define TGT   256
#define HID   512
#define TV    2000
#define VOC   3000
#define SRC   2048
#define SALL  2049
#define KPAD  2176    // keys rows per batch, padded to multiple of 128
#define APITCH 2064   // padded atten row pitch (float4-aligned)

typedef unsigned short u16;
typedef __attribute__((ext_vector_type(8))) short bf16x8;
typedef __attribute__((ext_vector_type(4))) float f32x4;

__device__ __forceinline__ u16 f2bf(float x) {
    unsigned u = __float_as_uint(x);
    u += 0x7FFFu + ((u >> 16) & 1u);
    return (u16)(u >> 16);
}

static __device__ __forceinline__ float gelu_exact(float x) {
    return 0.5f * x * (1.0f + erff(x * 0.70710678118654752f));
}

// async 16B global -> LDS (wave-uniform LDS base + lane*16)
__device__ __forceinline__ void gload16(const u16* g, u16* l) {
    __builtin_amdgcn_global_load_lds(
        (const __attribute__((address_space(1))) unsigned int*)g,
        (__attribute__((address_space(3))) unsigned int*)l,
        16, 0, 0);
}

// ---------------- PREP mega-kernel: casts + weight transposes + logits LSE ----------------
__device__ __forceinline__ void cast8_body(const float4* __restrict__ in,
                                           int4* __restrict__ out, int i) {
    float4 x = in[2 * i], y = in[2 * i + 1];
    unsigned p0 = (unsigned)f2bf(x.x) | ((unsigned)f2bf(x.y) << 16);
    unsigned p1 = (unsigned)f2bf(x.z) | ((unsigned)f2bf(x.w) << 16);
    unsigned p2 = (unsigned)f2bf(y.x) | ((unsigned)f2bf(y.y) << 16);
    unsigned p3 = (unsigned)f2bf(y.z) | ((unsigned)f2bf(y.w) << 16);
    out[i] = make_int4(p0, p1, p2, p3);
}

__global__ __launch_bounds__(256) void prep(
    const float* __restrict__ memory_raw, const float* __restrict__ feature,
    const float* __restrict__ Wk, const float* __restrict__ Wq,
    const float* __restrict__ logits,
    int4* __restrict__ a_mem, int4* __restrict__ featb,
    u16* __restrict__ wkT, u16* __restrict__ wqT, float* __restrict__ logZo)
{
    __shared__ float t[32][33];
    const int id = blockIdx.x;
    const int tid = threadIdx.x;
    if (id < 4096) {
        cast8_body((const float4*)memory_raw, a_mem, id * 256 + tid);
    } else if (id < 5120) {
        cast8_body((const float4*)feature, featb, (id - 4096) * 256 + tid);
    } else if (id < 5888) {
        const float* in; u16* outp; int rows, cols, bx, by;
        if (id < 5632) {
            int id2 = id - 5120;
            in = Wk; outp = wkT; rows = 512; cols = 1024;
            bx = (id2 & 31) * 32; by = (id2 >> 5) * 32;
        } else {
            int id2 = id - 5632;
            in = Wq; outp = wqT; rows = 512; cols = 512;
            bx = (id2 & 15) * 32; by = (id2 >> 4) * 32;
        }
        const int tx = tid & 31, ty = tid >> 5;
        #pragma unroll
        for (int k = 0; k < 4; ++k)
            t[ty + 8 * k][tx] = in[(size_t)(by + ty + 8 * k) * cols + bx + tx];
        __syncthreads();
        #pragma unroll
        for (int k = 0; k < 4; ++k)
            outp[(size_t)(bx + ty + 8 * k) * rows + by + tx] = f2bf(t[tx][ty + 8 * k]);
    } else {
        // k_logz: 4 rows per block, one wave per row (TV = 500 float4)
        const int row = (id - 5888) * 4 + (tid >> 6);
        const int lane = tid & 63;
        const float4* lrow4 = (const float4*)(logits + (size_t)row * TV);
        float4 v4[8];
        float m = -INFINITY;
        #pragma unroll
        for (int i = 0; i < 8; ++i) {
            int idx = lane + 64 * i;
            if (idx < 500) {
                v4[i] = lrow4[idx];
                m = fmaxf(m, fmaxf(fmaxf(v4[i].x, v4[i].y), fmaxf(v4[i].z, v4[i].w)));
            } else {
                v4[i] = make_float4(-INFINITY, -INFINITY, -INFINITY, -INFINITY);
            }
        }
        #pragma unroll
        for (int o = 32; o > 0; o >>= 1) m = fmaxf(m, __shfl_xor(m, o, 64));
        float s = 0.f;
        #pragma unroll
        for (int i = 0; i < 8; ++i) {
            s += __expf(v4[i].x - m) + __expf(v4[i].y - m)
               + __expf(v4[i].z - m) + __expf(v4[i].w - m);
        }
        #pragma unroll
        for (int o = 32; o > 0; o >>= 1) s += __shfl_xor(s, o, 64);
        if (lane == 0) logZo[row] = m + __logf(s);
    }
}

// ---------------- MFMA GEMM body (m97-style): global_load_lds + dbuf, 1 barrier/K-step ----------------
// C[M,N] = A[M,K=512] . B^T[N,K=512], 128x128 tile, BK=32, LDS linear [128][32] x2 buffers
template<int EPI>
__device__ __forceinline__ void gemm_body(
    int m0, int n0, int z,
    const u16* __restrict__ Abase, const u16* __restrict__ Bbase,
    const float* __restrict__ bias, float* __restrict__ outf, u16* __restrict__ outb,
    u16* __restrict__ As, u16* __restrict__ Bs)   // each 2*4096 u16
{
    const int tid = threadIdx.x;
    const int lane = tid & 63;
    const int w = tid >> 6;
    const int wr = (w >> 1) * 64, wc = (w & 1) * 64;

    const u16* Ag = Abase + (EPI == 2 ? (size_t)z * TGT * HID : 0);
    const u16* Bg = Bbase + (EPI == 2 ? (size_t)z * KPAD * HID : 0);

    // staging geometry: chunk c = w*2+q covers rows [c*16, c*16+16), lane -> row c*16 + lane/4,
    // col-chunk (lane&3)*8 elems. LDS dest base (wave-uniform) = buf + c*512 elems.
    const int chunkrow = lane >> 2;
    const int colc = (lane & 3) * 8;
    const int c0 = w * 2, c1 = c0 + 1;
    const u16* gA0 = Ag + (size_t)(m0 + c0 * 16 + chunkrow) * HID + colc;
    const u16* gA1 = Ag + (size_t)(m0 + c1 * 16 + chunkrow) * HID + colc;
    const u16* gB0 = Bg + (size_t)(n0 + c0 * 16 + chunkrow) * HID + colc;
    const u16* gB1 = Bg + (size_t)(n0 + c1 * 16 + chunkrow) * HID + colc;

    const int la = lane & 15, lb = lane >> 4;
    f32x4 acc[4][4] = {};

    // prologue stage of tile 0 into buf 0
    gload16(gA0, As + c0 * 512);
    gload16(gA1, As + c1 * 512);
    gload16(gB0, Bs + c0 * 512);
    gload16(gB1, Bs + c1 * 512);

    int cur = 0;
    for (int k0 = 0; k0 < HID; k0 += 32) {
        __syncthreads();   // drains vmcnt(0) (stage complete) + barrier
        const u16* Asb = As + cur * 4096;
        const u16* Bsb = Bs + cur * 4096;
        bf16x8 af[4], bfv[4];
        #pragma unroll
        for (int i = 0; i < 4; ++i)
            af[i] = *(const bf16x8*)(Asb + (wr + i * 16 + la) * 32 + lb * 8);
        #pragma unroll
        for (int j = 0; j < 4; ++j)
            bfv[j] = *(const bf16x8*)(Bsb + (wc + j * 16 + la) * 32 + lb * 8);
        if (k0 + 32 < HID) {
            const int nb = cur ^ 1;
            u16* An = As + nb * 4096;
            u16* Bn = Bs + nb * 4096;
            gload16(gA0 + k0 + 32, An + c0 * 512);
            gload16(gA1 + k0 + 32, An + c1 * 512);
            gload16(gB0 + k0 + 32, Bn + c0 * 512);
            gload16(gB1 + k0 + 32, Bn + c1 * 512);
        }
        #pragma unroll
        for (int i = 0; i < 4; ++i)
            #pragma unroll
            for (int j = 0; j < 4; ++j)
                acc[i][j] = __builtin_amdgcn_mfma_f32_16x16x32_bf16(af[i], bfv[j], acc[i][j], 0, 0, 0);
        cur ^= 1;
    }

    const int r_l = (lane >> 4) * 4, c_l = lane & 15;
    if (EPI == 0) {
        #pragma unroll
        for (int j = 0; j < 4; ++j) {
            const int n = n0 + wc + j * 16 + c_l;
            const float bv = bias[n];
            #pragma unroll
            for (int i = 0; i < 4; ++i)
                #pragma unroll
                for (int r = 0; r < 4; ++r) {
                    const int m = m0 + wr + i * 16 + r_l + r;
                    const int b = m >> 10, l = m & 1023;
                    const int s = 2 * l + (n >> 9), h = n & 511;
                    outb[((size_t)b * KPAD + s) * HID + h] = f2bf(acc[i][j][r] + bv);
                }
        }
    } else if (EPI == 1) {
        #pragma unroll
        for (int j = 0; j < 4; ++j) {
            const int n = n0 + wc + j * 16 + c_l;
            const float bv = bias[n];
            #pragma unroll
            for (int i = 0; i < 4; ++i)
                #pragma unroll
                for (int r = 0; r < 4; ++r) {
                    const int m = m0 + wr + i * 16 + r_l + r;
                    outb[(size_t)m * HID + n] = f2bf(gelu_exact(acc[i][j][r] + bv));
                }
        }
    } else {
        const float scale = 0.044194173824159216f;  // 1/sqrt(512)
        #pragma unroll
        for (int j = 0; j < 4; ++j) {
            const int s = n0 + wc + j * 16 + c_l;
            if (s < SALL) {
                #pragma unroll
                for (int i = 0; i < 4; ++i)
                    #pragma unroll
                    for (int r = 0; r < 4; ++r) {
                        const int t = m0 + wr + i * 16 + r_l + r;
                        outf[((size_t)(z * TGT + t)) * APITCH + s] = acc[i][j][r] * scale;
                    }
            }
        }
    }
}

// ---------------- merged keys-GEMM + query-GEMM + sentinel fill ----------------
// blocks: [0,1024) keys | [1024,1152) query | [1152,1168) fill_tail
__global__ __launch_bounds__(256) void gemms_a(
    const u16* __restrict__ a_mem, const u16* __restrict__ wkT, const float* __restrict__ bk,
    const u16* __restrict__ feat, const u16* __restrict__ wqT, const float* __restrict__ bq,
    const float* __restrict__ sent, u16* __restrict__ keysb, u16* __restrict__ queryb)
{
    __shared__ u16 As[2 * 4096];
    __shared__ u16 Bs[2 * 4096];
    const int id = blockIdx.x;
    if (id < 1024) {
        gemm_body<0>((id >> 3) * 128, (id & 7) * 128, 0, a_mem, wkT, bk, nullptr, keysb, As, Bs);
    } else if (id < 1152) {
        const int id2 = id - 1024;
        gemm_body<1>((id2 >> 2) * 128, (id2 & 3) * 128, 0, feat, wqT, bq, nullptr, queryb, As, Bs);
    } else {
        const int b = id - 1152;
        u16* kb = keysb + (size_t)b * KPAD * HID;
        for (int h = threadIdx.x; h < HID; h += 256)
            kb[(size_t)SRC * HID + h] = f2bf(sent[h]);
        int4* zp = (int4*)(kb + (size_t)SALL * HID);
        const int nz = (KPAD - SALL) * HID / 8;
        for (int i = threadIdx.x; i < nz; i += 256) zp[i] = make_int4(0, 0, 0, 0);
    }
}

// ---------------- atten GEMM ----------------
__global__ __launch_bounds__(256) void gemm_atten(
    const u16* __restrict__ Q, const u16* __restrict__ Keys, float* __restrict__ atten)
{
    __shared__ u16 As[2 * 4096];
    __shared__ u16 Bs[2 * 4096];
    gemm_body<2>(blockIdx.y * 128, blockIdx.x * 128, blockIdx.z,
                 Q, Keys, nullptr, atten, nullptr, As, Bs);
}

// ---------------- finalize: per (b,t) row, 128 threads, register-resident ----------------
__global__ __launch_bounds__(128, 6) void finalize(
    const float* __restrict__ atten, const int* __restrict__ ce,
    const float* __restrict__ out_logits, const float* __restrict__ logZo,
    float* __restrict__ out)
{
    __shared__ float p[VOC];
    __shared__ float red[2];
    const int bt = blockIdx.x;
    const int b = bt >> 8;
    const int tid = threadIdx.x;   // 0..127
    const float* arow = atten + (size_t)bt * APITCH;
    const float4* arow4 = (const float4*)arow;
    const int4* ce4 = (const int4*)(ce + (size_t)b * SRC);
    const float NEG = -1000000000.0f;
    const float EPSF = 1.1920929e-07f;
    const float FMINV = -3.4028234663852886e+38f;
    const int wid = tid >> 6, lane = tid & 63;

    float4* p4 = (float4*)p;
    #pragma unroll
    for (int k = 0; k < 6; ++k) {
        int idx = tid + 128 * k;
        if (idx < 750) p4[idx] = make_float4(0.f, 0.f, 0.f, 0.f);
    }

    const float sent_v = arow[SRC];
    float v[16];
    int ci[16];
    float mx = sent_v;
    #pragma unroll
    for (int k = 0; k < 4; ++k) {
        int idx = tid + 128 * k;
        float4 a4 = arow4[idx];
        int4 c4 = ce4[idx];
        float x0 = (c4.x == 0) ? NEG : a4.x;
        float x1 = (c4.y == 0) ? NEG : a4.y;
        float x2 = (c4.z == 0) ? NEG : a4.z;
        float x3 = (c4.w == 0) ? NEG : a4.w;
        v[4 * k + 0] = x0; v[4 * k + 1] = x1; v[4 * k + 2] = x2; v[4 * k + 3] = x3;
        ci[4 * k + 0] = c4.x; ci[4 * k + 1] = c4.y; ci[4 * k + 2] = c4.z; ci[4 * k + 3] = c4.w;
        mx = fmaxf(mx, fmaxf(fmaxf(x0, x1), fmaxf(x2, x3)));
    }
    #pragma unroll
    for (int o = 32; o > 0; o >>= 1) mx = fmaxf(mx, __shfl_down(mx, o, 64));
    __syncthreads();
    if (lane == 0) red[wid] = mx;
    __syncthreads();
    mx = fmaxf(red[0], red[1]);

    float sm = 0.f;
    #pragma unroll
    for (int i = 0; i < 16; ++i) {
        v[i] = __expf(v[i] - mx);
        sm += v[i];
    }
    if (tid == 0) sm += __expf(sent_v - mx);
    #pragma unroll
    for (int o = 32; o > 0; o >>= 1) sm += __shfl_down(sm, o, 64);
    __syncthreads();
    if (lane == 0) red[wid] = sm;
    __syncthreads();
    sm = red[0] + red[1];

    const float inv = 1.0f / sm;
    const float g = sent_v - (mx + __logf(sm));
    const float eg = __expf(g);

    #pragma unroll
    for (int i = 0; i < 16; ++i)
        if (ci[i] != 0) atomicAdd(&p[ci[i]], v[i] * inv);
    __syncthreads();

    const float lZo = logZo[bt];
    const float lg1p = log1pf(-eg + EPSF);
    const float lgm = __logf(1.0f - eg + EPSF);
    const float4* lrow4 = (const float4*)(out_logits + (size_t)bt * TV);
    float4* orow4 = (float4*)(out + (size_t)bt * VOC);
    #pragma unroll
    for (int k = 0; k < 6; ++k) {
        int idx = tid + 128 * k;
        if (idx >= 750) continue;
        float4 pv = p4[idx];
        float pal0 = __logf(pv.x + EPSF) - lg1p;
        float pal1 = __logf(pv.y + EPSF) - lg1p;
        float pal2 = __logf(pv.z + EPSF) - lg1p;
        float pal3 = __logf(pv.w + EPSF) - lg1p;
        if (isinf(pal0) && pal0 < 0.f) pal0 = FMINV;
        if (isinf(pal1) && pal1 < 0.f) pal1 = FMINV;
        if (isinf(pal2) && pal2 < 0.f) pal2 = FMINV;
        if (isinf(pal3) && pal3 < 0.f) pal3 = FMINV;
        float4 o;
        if (idx < 500) {
            float4 lv = lrow4[idx];
            float a0 = lv.x - lZo + g, b0 = pal0 + lgm;
            float a1 = lv.y - lZo + g, b1 = pal1 + lgm;
            float a2 = lv.z - lZo + g, b2 = pal2 + lgm;
            float a3 = lv.w - lZo + g, b3 = pal3 + lgm;
            float m0 = fmaxf(a0, b0), m1 = fmaxf(a1, b1);
            float m2 = fmaxf(a2, b2), m3 = fmaxf(a3, b3);
            o.x = m0 + __logf(__expf(a0 - m0) + __expf(b0 - m0));
            o.y = m1 + __logf(__expf(a1 - m1) + __expf(b1 - m1));
            o.z = m2 + __logf(__expf(a2 - m2) + __expf(b2 - m2));
            o.w = m3 + __logf(__expf(a3 - m3) + __expf(b3 - m3));
        } else {
            o.x = pal0 + lgm; o.y = pal1 + lgm;
            o.z = pal2 + lgm; o.w = pal3 + lgm;
        }
        orow4[idx] = o;
    }
}

extern "C" void kernel_launch(void* const* d_in, const int* in_sizes, int n_in,
                              void* d_out, int out_size, void* d_ws, size_t ws_size,
                              hipStream_t stream) {
    const float* out_logits = (const float*)d_in[0];
    const float* feature    = (const float*)d_in[1];
    const float* memory_raw = (const float*)d_in[2];
    const int*   content_e  = (const int*)d_in[3];
    const float* Wq = (const float*)d_in[4];
    const float* bq = (const float*)d_in[5];
    const float* Wk = (const float*)d_in[6];
    const float* bk = (const float*)d_in[7];
    const float* sentinel = (const float*)d_in[8];
    float* out = (float*)d_out;

    u16* a_mem  = (u16*)d_ws;                            // 16384*512
    u16* feat   = a_mem  + (size_t)16384 * 512;          // 4096*512
    u16* wkT    = feat   + (size_t)4096 * 512;           // 1024*512
    u16* wqT    = wkT    + (size_t)1024 * 512;           // 512*512
    u16* keysb  = wqT    + (size_t)512 * 512;            // 16*KPAD*512
    u16* queryb = keysb  + (size_t)BSZ * KPAD * HID;     // 4096*512
    float* atten = (float*)(queryb + (size_t)4096 * 512); // 16*256*APITCH f32
    float* logZo = atten + (size_t)BSZ * TGT * APITCH;   // 4096 f32

    prep<<<6912, 256, 0, stream>>>(memory_raw, feature, Wk, Wq, out_logits,
                                   (int4*)a_mem, (int4*)feat, wkT, wqT, logZo);
    gemms_a<<<1168, 256, 0, stream>>>(a_mem, wkT, bk, feat, wqT, bq,
                                      sentinel, keysb, queryb);
    gemm_atten<<<dim3(17, TGT / 128, BSZ), 256, 0, stream>>>(queryb, keysb, atten);
    finalize<<<BSZ * TGT, 128, 0, stream>>>(atten, content_e, out_logits, logZo, out);
}

// Round 6
// 135.570 us; speedup vs baseline: 3.5973x; 1.0368x over previous
//
#include <hip/hip_runtime.h>
#include <math.h>

#define BSZ   16
#define LSEQ  1024
#define TGT   256
#define HID   512
#define TV    2000
#define VOC   3000
#define SRC   2048
#define NKE   1280     // WkE rows: 2 j-halves x 640 (512 d + sentinel + bias + pad)
#define JOFF  640
#define SCALE 0.044194173824159216f   // 1/sqrt(512)

typedef unsigned short u16;
typedef __attribute__((ext_vector_type(8))) short bf16x8;
typedef __attribute__((ext_vector_type(4))) float f32x4;

__device__ __forceinline__ u16 f2bf(float x) {
    unsigned u = __float_as_uint(x);
    u += 0x7FFFu + ((u >> 16) & 1u);
    return (u16)(u >> 16);
}
__device__ __forceinline__ float bf2f(u16 x) {
    return __uint_as_float((unsigned)x << 16);
}

static __device__ __forceinline__ float gelu_exact(float x) {
    return 0.5f * x * (1.0f + erff(x * 0.70710678118654752f));
}

// async 16B global -> LDS (wave-uniform LDS base + lane*16)
__device__ __forceinline__ void gload16(const u16* g, u16* l) {
    __builtin_amdgcn_global_load_lds(
        (const __attribute__((address_space(1))) unsigned int*)g,
        (__attribute__((address_space(3))) unsigned int*)l,
        16, 0, 0);
}

// ---------------- PREP mega-kernel ----------------
// blocks: [0,4096) cast memory_raw | [4096,5120) cast feature | [5120,5376) Wq^T |
//         [5376,5696) WkE build | [5696,6720) k_logz | [6720,6736) ce_perm
__device__ __forceinline__ void cast8_body(const float4* __restrict__ in,
                                           int4* __restrict__ out, int i) {
    float4 x = in[2 * i], y = in[2 * i + 1];
    unsigned p0 = (unsigned)f2bf(x.x) | ((unsigned)f2bf(x.y) << 16);
    unsigned p1 = (unsigned)f2bf(x.z) | ((unsigned)f2bf(x.w) << 16);
    unsigned p2 = (unsigned)f2bf(y.x) | ((unsigned)f2bf(y.y) << 16);
    unsigned p3 = (unsigned)f2bf(y.z) | ((unsigned)f2bf(y.w) << 16);
    out[i] = make_int4(p0, p1, p2, p3);
}

__global__ __launch_bounds__(256) void prep(
    const float* __restrict__ memory_raw, const float* __restrict__ feature,
    const float* __restrict__ Wq, const float* __restrict__ Wk,
    const float* __restrict__ sentinel, const float* __restrict__ bk,
    const float* __restrict__ logits, const int* __restrict__ ce,
    int4* __restrict__ memb, int4* __restrict__ featb,
    u16* __restrict__ wqT, u16* __restrict__ wkE,
    float* __restrict__ logZo, int* __restrict__ ce_perm)
{
    __shared__ float t[32][33];
    const int id = blockIdx.x;
    const int tid = threadIdx.x;
    if (id < 4096) {
        cast8_body((const float4*)memory_raw, memb, id * 256 + tid);
    } else if (id < 5120) {
        cast8_body((const float4*)feature, featb, (id - 4096) * 256 + tid);
    } else if (id < 5376) {
        // Wq^T (512x512)
        int id2 = id - 5120;
        int bx = (id2 & 15) * 32, by = (id2 >> 4) * 32;
        const int tx = tid & 31, ty = tid >> 5;
        #pragma unroll
        for (int k = 0; k < 4; ++k)
            t[ty + 8 * k][tx] = Wq[(size_t)(by + ty + 8 * k) * 512 + bx + tx];
        __syncthreads();
        #pragma unroll
        for (int k = 0; k < 4; ++k)
            wqT[(size_t)(bx + ty + 8 * k) * 512 + by + tx] = f2bf(t[tx][ty + 8 * k]);
    } else if (id < 5696) {
        // WkE build: 4 rows per block, 64 threads x 8 cols per row
        const int rr = (id - 5376) * 4 + (tid >> 6);   // 0..1279
        const int c = (tid & 63) * 8;
        const int j = rr >= JOFF;
        const int dd = rr - j * JOFF;
        u16* dst = wkE + (size_t)rr * HID + c;
        if (dd < 512) {
            const float* src = Wk + (size_t)dd * 1024 + j * 512 + c;
            #pragma unroll
            for (int k = 0; k < 8; ++k) dst[k] = f2bf(src[k]);
        } else if (dd == 512) {
            #pragma unroll
            for (int k = 0; k < 8; ++k) dst[k] = f2bf(sentinel[c + k]);
        } else if (dd == 513) {
            #pragma unroll
            for (int k = 0; k < 8; ++k) dst[k] = f2bf(bk[j * 512 + c + k]);
        } else {
            #pragma unroll
            for (int k = 0; k < 8; ++k) dst[k] = 0;
        }
    } else if (id < 6720) {
        // k_logz: 4 rows per block, one wave per row (TV = 500 float4)
        const int row = (id - 5696) * 4 + (tid >> 6);
        const int lane = tid & 63;
        const float4* lrow4 = (const float4*)(logits + (size_t)row * TV);
        float4 v4[8];
        float m = -INFINITY;
        #pragma unroll
        for (int i = 0; i < 8; ++i) {
            int idx = lane + 64 * i;
            if (idx < 500) {
                v4[i] = lrow4[idx];
                m = fmaxf(m, fmaxf(fmaxf(v4[i].x, v4[i].y), fmaxf(v4[i].z, v4[i].w)));
            } else {
                v4[i] = make_float4(-INFINITY, -INFINITY, -INFINITY, -INFINITY);
            }
        }
        #pragma unroll
        for (int o = 32; o > 0; o >>= 1) m = fmaxf(m, __shfl_xor(m, o, 64));
        float s = 0.f;
        #pragma unroll
        for (int i = 0; i < 8; ++i) {
            s += __expf(v4[i].x - m) + __expf(v4[i].y - m)
               + __expf(v4[i].z - m) + __expf(v4[i].w - m);
        }
        #pragma unroll
        for (int o = 32; o > 0; o >>= 1) s += __shfl_xor(s, o, 64);
        if (lane == 0) logZo[row] = m + __logf(s);
    } else {
        // ce_perm: ce_perm[b][j*1024+l] = ce[b][2l+j]
        const int b = id - 6720;
        const int* ceb = ce + (size_t)b * SRC;
        int* cpb = ce_perm + (size_t)b * SRC;
        for (int jl = tid; jl < SRC; jl += 256) {
            int j = jl >> 10, l = jl & 1023;
            cpb[jl] = ceb[2 * l + j];
        }
    }
}

// ---------------- MFMA GEMM body: C = A[M,512] . B^T[N,512], 128x128 tile ----------------
// EPI 1: query (+bq, gelu) -> bf16 [m][512]
// EPI 3: qk (plain)        -> bf16 [m][1280]
// EPI 2: atten (bias-gather + scale) -> f32 atten[b*256+t][jj*1024+l], z=(b,jj)
template<int EPI, int LDA>
__device__ __forceinline__ void gemm_body(
    int m0, int n0, int z,
    const u16* __restrict__ Abase, const u16* __restrict__ Bbase,
    const float* __restrict__ bias, float* __restrict__ outf, u16* __restrict__ outb,
    u16* __restrict__ As, u16* __restrict__ Bs)   // each 2*4096 u16
{
    const int tid = threadIdx.x;
    const int lane = tid & 63;
    const int w = tid >> 6;
    const int wr = (w >> 1) * 64, wc = (w & 1) * 64;

    const u16* Ag = Abase;
    const u16* Bg = Bbase;
    if (EPI == 2) {
        Ag = Abase + (size_t)(z >> 1) * TGT * NKE + (size_t)(z & 1) * JOFF;
        Bg = Bbase + (size_t)(z >> 1) * LSEQ * HID;
    }

    const int chunkrow = lane >> 2;
    const int colc = (lane & 3) * 8;
    const int c0 = w * 2, c1 = c0 + 1;
    const u16* gA0 = Ag + (size_t)(m0 + c0 * 16 + chunkrow) * LDA + colc;
    const u16* gA1 = Ag + (size_t)(m0 + c1 * 16 + chunkrow) * LDA + colc;
    const u16* gB0 = Bg + (size_t)(n0 + c0 * 16 + chunkrow) * HID + colc;
    const u16* gB1 = Bg + (size_t)(n0 + c1 * 16 + chunkrow) * HID + colc;

    const int la = lane & 15, lb = lane >> 4;
    f32x4 acc[4][4] = {};

    gload16(gA0, As + c0 * 512);
    gload16(gA1, As + c1 * 512);
    gload16(gB0, Bs + c0 * 512);
    gload16(gB1, Bs + c1 * 512);

    int cur = 0;
    for (int k0 = 0; k0 < HID; k0 += 32) {
        __syncthreads();   // drains vmcnt(0) (stage complete) + barrier
        const u16* Asb = As + cur * 4096;
        const u16* Bsb = Bs + cur * 4096;
        bf16x8 af[4], bfv[4];
        #pragma unroll
        for (int i = 0; i < 4; ++i)
            af[i] = *(const bf16x8*)(Asb + (wr + i * 16 + la) * 32 + lb * 8);
        #pragma unroll
        for (int j = 0; j < 4; ++j)
            bfv[j] = *(const bf16x8*)(Bsb + (wc + j * 16 + la) * 32 + lb * 8);
        if (k0 + 32 < HID) {
            const int nb = cur ^ 1;
            u16* An = As + nb * 4096;
            u16* Bn = Bs + nb * 4096;
            gload16(gA0 + k0 + 32, An + c0 * 512);
            gload16(gA1 + k0 + 32, An + c1 * 512);
            gload16(gB0 + k0 + 32, Bn + c0 * 512);
            gload16(gB1 + k0 + 32, Bn + c1 * 512);
        }
        #pragma unroll
        for (int i = 0; i < 4; ++i)
            #pragma unroll
            for (int j = 0; j < 4; ++j)
                acc[i][j] = __builtin_amdgcn_mfma_f32_16x16x32_bf16(af[i], bfv[j], acc[i][j], 0, 0, 0);
        cur ^= 1;
    }

    const int r_l = (lane >> 4) * 4, c_l = lane & 15;
    if (EPI == 1) {
        #pragma unroll
        for (int j = 0; j < 4; ++j) {
            const int n = n0 + wc + j * 16 + c_l;
            const float bv = bias[n];
            #pragma unroll
            for (int i = 0; i < 4; ++i)
                #pragma unroll
                for (int r = 0; r < 4; ++r) {
                    const int m = m0 + wr + i * 16 + r_l + r;
                    outb[(size_t)m * HID + n] = f2bf(gelu_exact(acc[i][j][r] + bv));
                }
        }
    } else if (EPI == 3) {
        #pragma unroll
        for (int j = 0; j < 4; ++j) {
            const int n = n0 + wc + j * 16 + c_l;
            #pragma unroll
            for (int i = 0; i < 4; ++i)
                #pragma unroll
                for (int r = 0; r < 4; ++r) {
                    const int m = m0 + wr + i * 16 + r_l + r;
                    outb[(size_t)m * NKE + n] = f2bf(acc[i][j][r]);
                }
        }
    } else {
        const int b = z >> 1, jj = z & 1;
        // bias_j[t] = qk[b*256+t][jj*640+513], gathered once per row
        float biasr[4][4];
        #pragma unroll
        for (int i = 0; i < 4; ++i)
            #pragma unroll
            for (int r = 0; r < 4; ++r) {
                const int tt = m0 + wr + i * 16 + r_l + r;
                biasr[i][r] = bf2f(Abase[(size_t)(b * TGT + tt) * NKE + jj * JOFF + 513]);
            }
        #pragma unroll
        for (int j = 0; j < 4; ++j) {
            const int l = n0 + wc + j * 16 + c_l;
            #pragma unroll
            for (int i = 0; i < 4; ++i)
                #pragma unroll
                for (int r = 0; r < 4; ++r) {
                    const int tt = m0 + wr + i * 16 + r_l + r;
                    outf[(size_t)(b * TGT + tt) * SRC + jj * 1024 + l] =
                        (acc[i][j][r] + biasr[i][r]) * SCALE;
                }
        }
    }
}

__global__ __launch_bounds__(256) void gemm_query(
    const u16* __restrict__ feat, const u16* __restrict__ wqT,
    const float* __restrict__ bq, u16* __restrict__ queryb)
{
    __shared__ u16 As[2 * 4096];
    __shared__ u16 Bs[2 * 4096];
    gemm_body<1, 512>(blockIdx.y * 128, blockIdx.x * 128, 0,
                      feat, wqT, bq, nullptr, queryb, As, Bs);
}

__global__ __launch_bounds__(256) void gemm_qk(
    const u16* __restrict__ queryb, const u16* __restrict__ wkE,
    u16* __restrict__ qkb)
{
    __shared__ u16 As[2 * 4096];
    __shared__ u16 Bs[2 * 4096];
    gemm_body<3, 512>(blockIdx.y * 128, blockIdx.x * 128, 0,
                      queryb, wkE, nullptr, nullptr, qkb, As, Bs);
}

__global__ __launch_bounds__(256) void gemm_atten(
    const u16* __restrict__ qkb, const u16* __restrict__ memb,
    float* __restrict__ atten)
{
    __shared__ u16 As[2 * 4096];
    __shared__ u16 Bs[2 * 4096];
    gemm_body<2, NKE>(blockIdx.y * 128, blockIdx.x * 128, blockIdx.z,
                      qkb, memb, nullptr, atten, nullptr, As, Bs);
}

// ---------------- finalize: per (b,t) row, 128 threads, register-resident ----------------
__global__ __launch_bounds__(128, 6) void finalize(
    const float* __restrict__ atten, const int* __restrict__ ce_perm,
    const u16* __restrict__ qkb,
    const float* __restrict__ out_logits, const float* __restrict__ logZo,
    float* __restrict__ out)
{
    __shared__ float p[VOC];
    __shared__ float red[2];
    const int bt = blockIdx.x;
    const int b = bt >> 8;
    const int tid = threadIdx.x;   // 0..127
    const float4* arow4 = (const float4*)(atten + (size_t)bt * SRC);
    const int4* ce4 = (const int4*)(ce_perm + (size_t)b * SRC);
    const float NEG = -1000000000.0f;
    const float EPSF = 1.1920929e-07f;
    const float FMINV = -3.4028234663852886e+38f;
    const int wid = tid >> 6, lane = tid & 63;

    float4* p4 = (float4*)p;
    #pragma unroll
    for (int k = 0; k < 6; ++k) {
        int idx = tid + 128 * k;
        if (idx < 750) p4[idx] = make_float4(0.f, 0.f, 0.f, 0.f);
    }

    const float sent_v = bf2f(qkb[(size_t)bt * NKE + 512]) * SCALE;
    float v[16];
    int ci[16];
    float mx = sent_v;
    #pragma unroll
    for (int k = 0; k < 4; ++k) {
        int idx = tid + 128 * k;
        float4 a4 = arow4[idx];
        int4 c4 = ce4[idx];
        float x0 = (c4.x == 0) ? NEG : a4.x;
        float x1 = (c4.y == 0) ? NEG : a4.y;
        float x2 = (c4.z == 0) ? NEG : a4.z;
        float x3 = (c4.w == 0) ? NEG : a4.w;
        v[4 * k + 0] = x0; v[4 * k + 1] = x1; v[4 * k + 2] = x2; v[4 * k + 3] = x3;
        ci[4 * k + 0] = c4.x; ci[4 * k + 1] = c4.y; ci[4 * k + 2] = c4.z; ci[4 * k + 3] = c4.w;
        mx = fmaxf(mx, fmaxf(fmaxf(x0, x1), fmaxf(x2, x3)));
    }
    #pragma unroll
    for (int o = 32; o > 0; o >>= 1) mx = fmaxf(mx, __shfl_down(mx, o, 64));
    __syncthreads();
    if (lane == 0) red[wid] = mx;
    __syncthreads();
    mx = fmaxf(red[0], red[1]);

    float sm = 0.f;
    #pragma unroll
    for (int i = 0; i < 16; ++i) {
        v[i] = __expf(v[i] - mx);
        sm += v[i];
    }
    if (tid == 0) sm += __expf(sent_v - mx);
    #pragma unroll
    for (int o = 32; o > 0; o >>= 1) sm += __shfl_down(sm, o, 64);
    __syncthreads();
    if (lane == 0) red[wid] = sm;
    __syncthreads();
    sm = red[0] + red[1];

    const float inv = 1.0f / sm;
    const float g = sent_v - (mx + __logf(sm));
    const float eg = __expf(g);

    #pragma unroll
    for (int i = 0; i < 16; ++i)
        if (ci[i] != 0) atomicAdd(&p[ci[i]], v[i] * inv);
    __syncthreads();

    const float lZo = logZo[bt];
    const float lg1p = log1pf(-eg + EPSF);
    const float lgm = __logf(1.0f - eg + EPSF);
    const float4* lrow4 = (const float4*)(out_logits + (size_t)bt * TV);
    float4* orow4 = (float4*)(out + (size_t)bt * VOC);
    #pragma unroll
    for (int k = 0; k < 6; ++k) {
        int idx = tid + 128 * k;
        if (idx >= 750) continue;
        float4 pv = p4[idx];
        float pal0 = __logf(pv.x + EPSF) - lg1p;
        float pal1 = __logf(pv.y + EPSF) - lg1p;
        float pal2 = __logf(pv.z + EPSF) - lg1p;
        float pal3 = __logf(pv.w + EPSF) - lg1p;
        if (isinf(pal0) && pal0 < 0.f) pal0 = FMINV;
        if (isinf(pal1) && pal1 < 0.f) pal1 = FMINV;
        if (isinf(pal2) && pal2 < 0.f) pal2 = FMINV;
        if (isinf(pal3) && pal3 < 0.f) pal3 = FMINV;
        float4 o;
        if (idx < 500) {
            float4 lv = lrow4[idx];
            float a0 = lv.x - lZo + g, b0 = pal0 + lgm;
            float a1 = lv.y - lZo + g, b1 = pal1 + lgm;
            float a2 = lv.z - lZo + g, b2 = pal2 + lgm;
            float a3 = lv.w - lZo + g, b3 = pal3 + lgm;
            float m0 = fmaxf(a0, b0), m1 = fmaxf(a1, b1);
            float m2 = fmaxf(a2, b2), m3 = fmaxf(a3, b3);
            o.x = m0 + __logf(__expf(a0 - m0) + __expf(b0 - m0));
            o.y = m1 + __logf(__expf(a1 - m1) + __expf(b1 - m1));
            o.z = m2 + __logf(__expf(a2 - m2) + __expf(b2 - m2));
            o.w = m3 + __logf(__expf(a3 - m3) + __expf(b3 - m3));
        } else {
            o.x = pal0 + lgm; o.y = pal1 + lgm;
            o.z = pal2 + lgm; o.w = pal3 + lgm;
        }
        orow4[idx] = o;
    }
}

extern "C" void kernel_launch(void* const* d_in, const int* in_sizes, int n_in,
                              void* d_out, int out_size, void* d_ws, size_t ws_size,
                              hipStream_t stream) {
    const float* out_logits = (const float*)d_in[0];
    const float* feature    = (const float*)d_in[1];
    const float* memory_raw = (const float*)d_in[2];
    const int*   content_e  = (const int*)d_in[3];
    const float* Wq = (const float*)d_in[4];
    const float* bq = (const float*)d_in[5];
    const float* Wk = (const float*)d_in[6];
    const float* bk = (const float*)d_in[7];
    const float* sentinel = (const float*)d_in[8];
    float* out = (float*)d_out;

    u16* memb   = (u16*)d_ws;                             // 16384*512 bf16
    u16* featb  = memb   + (size_t)16384 * 512;           // 4096*512
    u16* wqT    = featb  + (size_t)4096 * 512;            // 512*512
    u16* wkE    = wqT    + (size_t)512 * 512;             // 1280*512
    u16* queryb = wkE    + (size_t)NKE * 512;             // 4096*512
    u16* qkb    = queryb + (size_t)4096 * 512;            // 4096*1280
    float* atten = (float*)(qkb + (size_t)4096 * NKE);    // 4096*2048 f32
    float* logZo = atten + (size_t)4096 * SRC;            // 4096 f32
    int* ce_perm = (int*)(logZo + 4096);                  // 16*2048 int

    prep<<<6736, 256, 0, stream>>>(memory_raw, feature, Wq, Wk, sentinel, bk,
                                   out_logits, content_e,
                                   (int4*)memb, (int4*)featb, wqT, wkE, logZo, ce_perm);
    gemm_query<<<dim3(4, 32), 256, 0, stream>>>(featb, wqT, bq, queryb);
    gemm_qk<<<dim3(10, 32), 256, 0, stream>>>(queryb, wkE, qkb);
    gemm_atten<<<dim3(8, 2, 32), 256, 0, stream>>>(qkb, memb, atten);
    finalize<<<BSZ * TGT, 128, 0, stream>>>(atten, ce_perm, qkb, out_logits, logZo, out);
}

// Round 7
// 123.415 us; speedup vs baseline: 3.9516x; 1.0985x over previous
//
#include <hip/hip_runtime.h>
#include <math.h>

#define BSZ   16
#define LSEQ  1024
#define TGT   256
#define HID   512
#define TV    2000
#define VOC   3000
#define SRC   2048
#define NKE   1280     // WkE rows: 2 j-halves x 640 (512 d + sentinel + bias + pad)
#define JOFF  640
#define SCALE 0.044194173824159216f   // 1/sqrt(512)

typedef unsigned short u16;
typedef __attribute__((ext_vector_type(8))) short bf16x8;
typedef __attribute__((ext_vector_type(4))) float f32x4;

__device__ __forceinline__ u16 f2bf(float x) {
    unsigned u = __float_as_uint(x);
    u += 0x7FFFu + ((u >> 16) & 1u);
    return (u16)(u >> 16);
}
__device__ __forceinline__ float bf2f(u16 x) {
    return __uint_as_float((unsigned)x << 16);
}

static __device__ __forceinline__ float gelu_exact(float x) {
    return 0.5f * x * (1.0f + erff(x * 0.70710678118654752f));
}

// async 16B global -> LDS (wave-uniform LDS base + lane*16)
__device__ __forceinline__ void gload16(const u16* g, u16* l) {
    __builtin_amdgcn_global_load_lds(
        (const __attribute__((address_space(1))) unsigned int*)g,
        (__attribute__((address_space(3))) unsigned int*)l,
        16, 0, 0);
}

// ---------------- PREP mega-kernel ----------------
// blocks: [0,4096) cast memory_raw | [4096,5120) cast feature | [5120,5376) Wq^T |
//         [5376,5696) WkE build | [5696,6720) k_logz | [6720,6736) ce_perm | 6736 rowsum=0
__device__ __forceinline__ void cast8_body(const float4* __restrict__ in,
                                           int4* __restrict__ out, int i) {
    float4 x = in[2 * i], y = in[2 * i + 1];
    unsigned p0 = (unsigned)f2bf(x.x) | ((unsigned)f2bf(x.y) << 16);
    unsigned p1 = (unsigned)f2bf(x.z) | ((unsigned)f2bf(x.w) << 16);
    unsigned p2 = (unsigned)f2bf(y.x) | ((unsigned)f2bf(y.y) << 16);
    unsigned p3 = (unsigned)f2bf(y.z) | ((unsigned)f2bf(y.w) << 16);
    out[i] = make_int4(p0, p1, p2, p3);
}

__global__ __launch_bounds__(256) void prep(
    const float* __restrict__ memory_raw, const float* __restrict__ feature,
    const float* __restrict__ Wq, const float* __restrict__ Wk,
    const float* __restrict__ sentinel, const float* __restrict__ bk,
    const float* __restrict__ logits, const int* __restrict__ ce,
    int4* __restrict__ memb, int4* __restrict__ featb,
    u16* __restrict__ wqT, u16* __restrict__ wkE,
    float* __restrict__ logZo, int* __restrict__ ce_perm,
    float* __restrict__ rowsum)
{
    __shared__ float t[32][33];
    const int id = blockIdx.x;
    const int tid = threadIdx.x;
    if (id < 4096) {
        cast8_body((const float4*)memory_raw, memb, id * 256 + tid);
    } else if (id < 5120) {
        cast8_body((const float4*)feature, featb, (id - 4096) * 256 + tid);
    } else if (id < 5376) {
        // Wq^T (512x512)
        int id2 = id - 5120;
        int bx = (id2 & 15) * 32, by = (id2 >> 4) * 32;
        const int tx = tid & 31, ty = tid >> 5;
        #pragma unroll
        for (int k = 0; k < 4; ++k)
            t[ty + 8 * k][tx] = Wq[(size_t)(by + ty + 8 * k) * 512 + bx + tx];
        __syncthreads();
        #pragma unroll
        for (int k = 0; k < 4; ++k)
            wqT[(size_t)(bx + ty + 8 * k) * 512 + by + tx] = f2bf(t[tx][ty + 8 * k]);
    } else if (id < 5696) {
        // WkE build: 4 rows per block, 64 threads x 8 cols per row
        const int rr = (id - 5376) * 4 + (tid >> 6);   // 0..1279
        const int c = (tid & 63) * 8;
        const int j = rr >= JOFF;
        const int dd = rr - j * JOFF;
        u16* dst = wkE + (size_t)rr * HID + c;
        if (dd < 512) {
            const float* src = Wk + (size_t)dd * 1024 + j * 512 + c;
            #pragma unroll
            for (int k = 0; k < 8; ++k) dst[k] = f2bf(src[k]);
        } else if (dd == 512) {
            #pragma unroll
            for (int k = 0; k < 8; ++k) dst[k] = f2bf(sentinel[c + k]);
        } else if (dd == 513) {
            #pragma unroll
            for (int k = 0; k < 8; ++k) dst[k] = f2bf(bk[j * 512 + c + k]);
        } else {
            #pragma unroll
            for (int k = 0; k < 8; ++k) dst[k] = 0;
        }
    } else if (id < 6720) {
        // k_logz: 4 rows per block, one wave per row (TV = 500 float4)
        const int row = (id - 5696) * 4 + (tid >> 6);
        const int lane = tid & 63;
        const float4* lrow4 = (const float4*)(logits + (size_t)row * TV);
        float4 v4[8];
        float m = -INFINITY;
        #pragma unroll
        for (int i = 0; i < 8; ++i) {
            int idx = lane + 64 * i;
            if (idx < 500) {
                v4[i] = lrow4[idx];
                m = fmaxf(m, fmaxf(fmaxf(v4[i].x, v4[i].y), fmaxf(v4[i].z, v4[i].w)));
            } else {
                v4[i] = make_float4(-INFINITY, -INFINITY, -INFINITY, -INFINITY);
            }
        }
        #pragma unroll
        for (int o = 32; o > 0; o >>= 1) m = fmaxf(m, __shfl_xor(m, o, 64));
        float s = 0.f;
        #pragma unroll
        for (int i = 0; i < 8; ++i) {
            s += __expf(v4[i].x - m) + __expf(v4[i].y - m)
               + __expf(v4[i].z - m) + __expf(v4[i].w - m);
        }
        #pragma unroll
        for (int o = 32; o > 0; o >>= 1) s += __shfl_xor(s, o, 64);
        if (lane == 0) logZo[row] = m + __logf(s);
    } else if (id < 6736) {
        // ce_perm: ce_perm[b][j*1024+l] = ce[b][2l+j]
        const int b = id - 6720;
        const int* ceb = ce + (size_t)b * SRC;
        int* cpb = ce_perm + (size_t)b * SRC;
        for (int jl = tid; jl < SRC; jl += 256) {
            int j = jl >> 10, l = jl & 1023;
            cpb[jl] = ceb[2 * l + j];
        }
    } else {
        // zero rowsum (4096 f32 = 1024 float4) — fresh every launch
        float4* rz = (float4*)rowsum;
        for (int i = tid; i < 1024; i += 256) rz[i] = make_float4(0.f, 0.f, 0.f, 0.f);
    }
}

// ---------------- MFMA GEMM body: C = A[M,512] . B^T[N,512], 128x128 tile ----------------
// EPI 1: query (+bq, gelu) -> bf16 [m][512]
// EPI 3: qk (plain)        -> bf16 [m][1280]
// EPI 2: atten (bias + scale + EXP + mask + row-partial-sum) -> f32 e-values, z=(b,jj)
template<int EPI, int LDA>
__device__ __forceinline__ void gemm_body(
    int m0, int n0, int z,
    const u16* __restrict__ Abase, const u16* __restrict__ Bbase,
    const float* __restrict__ bias, float* __restrict__ outf, u16* __restrict__ outb,
    const int* __restrict__ ce_perm, float* __restrict__ rowsum,
    u16* __restrict__ As, u16* __restrict__ Bs)   // each 2*4096 u16
{
    const int tid = threadIdx.x;
    const int lane = tid & 63;
    const int w = tid >> 6;
    const int wr = (w >> 1) * 64, wc = (w & 1) * 64;

    const u16* Ag = Abase;
    const u16* Bg = Bbase;
    if (EPI == 2) {
        Ag = Abase + (size_t)(z >> 1) * TGT * NKE + (size_t)(z & 1) * JOFF;
        Bg = Bbase + (size_t)(z >> 1) * LSEQ * HID;
    }

    const int chunkrow = lane >> 2;
    const int colc = (lane & 3) * 8;
    const int c0 = w * 2, c1 = c0 + 1;
    const u16* gA0 = Ag + (size_t)(m0 + c0 * 16 + chunkrow) * LDA + colc;
    const u16* gA1 = Ag + (size_t)(m0 + c1 * 16 + chunkrow) * LDA + colc;
    const u16* gB0 = Bg + (size_t)(n0 + c0 * 16 + chunkrow) * HID + colc;
    const u16* gB1 = Bg + (size_t)(n0 + c1 * 16 + chunkrow) * HID + colc;

    const int la = lane & 15, lb = lane >> 4;
    f32x4 acc[4][4] = {};

    gload16(gA0, As + c0 * 512);
    gload16(gA1, As + c1 * 512);
    gload16(gB0, Bs + c0 * 512);
    gload16(gB1, Bs + c1 * 512);

    int cur = 0;
    for (int k0 = 0; k0 < HID; k0 += 32) {
        __syncthreads();   // drains vmcnt(0) (stage complete) + barrier
        const u16* Asb = As + cur * 4096;
        const u16* Bsb = Bs + cur * 4096;
        bf16x8 af[4], bfv[4];
        #pragma unroll
        for (int i = 0; i < 4; ++i)
            af[i] = *(const bf16x8*)(Asb + (wr + i * 16 + la) * 32 + lb * 8);
        #pragma unroll
        for (int j = 0; j < 4; ++j)
            bfv[j] = *(const bf16x8*)(Bsb + (wc + j * 16 + la) * 32 + lb * 8);
        if (k0 + 32 < HID) {
            const int nb = cur ^ 1;
            u16* An = As + nb * 4096;
            u16* Bn = Bs + nb * 4096;
            gload16(gA0 + k0 + 32, An + c0 * 512);
            gload16(gA1 + k0 + 32, An + c1 * 512);
            gload16(gB0 + k0 + 32, Bn + c0 * 512);
            gload16(gB1 + k0 + 32, Bn + c1 * 512);
        }
        #pragma unroll
        for (int i = 0; i < 4; ++i)
            #pragma unroll
            for (int j = 0; j < 4; ++j)
                acc[i][j] = __builtin_amdgcn_mfma_f32_16x16x32_bf16(af[i], bfv[j], acc[i][j], 0, 0, 0);
        cur ^= 1;
    }

    const int r_l = (lane >> 4) * 4, c_l = lane & 15;
    if (EPI == 1) {
        #pragma unroll
        for (int j = 0; j < 4; ++j) {
            const int n = n0 + wc + j * 16 + c_l;
            const float bv = bias[n];
            #pragma unroll
            for (int i = 0; i < 4; ++i)
                #pragma unroll
                for (int r = 0; r < 4; ++r) {
                    const int m = m0 + wr + i * 16 + r_l + r;
                    outb[(size_t)m * HID + n] = f2bf(gelu_exact(acc[i][j][r] + bv));
                }
        }
    } else if (EPI == 3) {
        #pragma unroll
        for (int j = 0; j < 4; ++j) {
            const int n = n0 + wc + j * 16 + c_l;
            #pragma unroll
            for (int i = 0; i < 4; ++i)
                #pragma unroll
                for (int r = 0; r < 4; ++r) {
                    const int m = m0 + wr + i * 16 + r_l + r;
                    outb[(size_t)m * NKE + n] = f2bf(acc[i][j][r]);
                }
        }
    } else {
        const int b = z >> 1, jj = z & 1;
        // per-row bias (q.bk_j) gathered from qk row; per-col mask from ce_perm
        float biasr[4][4];
        #pragma unroll
        for (int i = 0; i < 4; ++i)
            #pragma unroll
            for (int r = 0; r < 4; ++r) {
                const int tt = m0 + wr + i * 16 + r_l + r;
                biasr[i][r] = bf2f(Abase[(size_t)(b * TGT + tt) * NKE + jj * JOFF + 513]);
            }
        int cj[4];
        #pragma unroll
        for (int j = 0; j < 4; ++j)
            cj[j] = ce_perm[(size_t)b * SRC + jj * 1024 + n0 + wc + j * 16 + c_l];
        #pragma unroll
        for (int i = 0; i < 4; ++i)
            #pragma unroll
            for (int r = 0; r < 4; ++r) {
                const int tt = m0 + wr + i * 16 + r_l + r;
                float rs = 0.f;
                #pragma unroll
                for (int j = 0; j < 4; ++j) {
                    const int l = n0 + wc + j * 16 + c_l;
                    float ev = (cj[j] == 0) ? 0.f
                             : __expf((acc[i][j][r] + biasr[i][r]) * SCALE);
                    outf[(size_t)(b * TGT + tt) * SRC + jj * 1024 + l] = ev;
                    rs += ev;
                }
                rs += __shfl_xor(rs, 1, 64);
                rs += __shfl_xor(rs, 2, 64);
                rs += __shfl_xor(rs, 4, 64);
                rs += __shfl_xor(rs, 8, 64);
                if (c_l == 0) atomicAdd(&rowsum[b * TGT + tt], rs);
            }
    }
}

__global__ __launch_bounds__(256) void gemm_query(
    const u16* __restrict__ feat, const u16* __restrict__ wqT,
    const float* __restrict__ bq, u16* __restrict__ queryb)
{
    __shared__ u16 As[2 * 4096];
    __shared__ u16 Bs[2 * 4096];
    gemm_body<1, 512>(blockIdx.y * 128, blockIdx.x * 128, 0,
                      feat, wqT, bq, nullptr, queryb, nullptr, nullptr, As, Bs);
}

__global__ __launch_bounds__(256) void gemm_qk(
    const u16* __restrict__ queryb, const u16* __restrict__ wkE,
    u16* __restrict__ qkb)
{
    __shared__ u16 As[2 * 4096];
    __shared__ u16 Bs[2 * 4096];
    gemm_body<3, 512>(blockIdx.y * 128, blockIdx.x * 128, 0,
                      queryb, wkE, nullptr, nullptr, qkb, nullptr, nullptr, As, Bs);
}

__global__ __launch_bounds__(256) void gemm_atten(
    const u16* __restrict__ qkb, const u16* __restrict__ memb,
    const int* __restrict__ ce_perm, float* __restrict__ rowsum,
    float* __restrict__ atten_e)
{
    __shared__ u16 As[2 * 4096];
    __shared__ u16 Bs[2 * 4096];
    gemm_body<2, NKE>(blockIdx.y * 128, blockIdx.x * 128, blockIdx.z,
                      qkb, memb, nullptr, atten_e, nullptr, ce_perm, rowsum, As, Bs);
}

// ---------------- finalize: per (b,t) row, reduction-free ----------------
__global__ __launch_bounds__(256) void finalize(
    const float* __restrict__ atten_e, const int* __restrict__ ce_perm,
    const u16* __restrict__ qkb, const float* __restrict__ rowsum,
    const float* __restrict__ out_logits, const float* __restrict__ logZo,
    float* __restrict__ out)
{
    __shared__ float p[VOC];
    const int bt = blockIdx.x;
    const int b = bt >> 8;
    const int tid = threadIdx.x;   // 0..255
    const float EPSF = 1.1920929e-07f;

    float4* p4 = (float4*)p;
    #pragma unroll
    for (int k = 0; k < 3; ++k) {
        int idx = tid + 256 * k;
        if (idx < 750) p4[idx] = make_float4(0.f, 0.f, 0.f, 0.f);
    }

    // row stats from precomputed rowsum (no block reductions)
    const float sent_v = bf2f(qkb[(size_t)bt * NKE + 512]) * SCALE;
    const float se = __expf(sent_v);
    const float sm = rowsum[bt] + se;
    const float inv = 1.0f / sm;
    const float g = sent_v - __logf(sm);   // log gate
    const float eg = se * inv;
    const float lg1p = log1pf(-eg + EPSF);
    const float lgm = __logf(1.0f - eg + EPSF);
    const float lZo = logZo[bt];

    const float4* arow4 = (const float4*)(atten_e + (size_t)bt * SRC);
    const int4* ce4 = (const int4*)(ce_perm + (size_t)b * SRC);
    __syncthreads();
    #pragma unroll
    for (int k = 0; k < 2; ++k) {
        int idx = tid + 256 * k;
        float4 a4 = arow4[idx];
        int4 c4 = ce4[idx];
        if (c4.x != 0) atomicAdd(&p[c4.x], a4.x * inv);
        if (c4.y != 0) atomicAdd(&p[c4.y], a4.y * inv);
        if (c4.z != 0) atomicAdd(&p[c4.z], a4.z * inv);
        if (c4.w != 0) atomicAdd(&p[c4.w], a4.w * inv);
    }
    __syncthreads();

    const float4* lrow4 = (const float4*)(out_logits + (size_t)bt * TV);
    float4* orow4 = (float4*)(out + (size_t)bt * VOC);
    #pragma unroll
    for (int k = 0; k < 3; ++k) {
        int idx = tid + 256 * k;
        if (idx >= 750) continue;
        float4 pv = p4[idx];
        float pal0 = __logf(pv.x + EPSF) - lg1p;
        float pal1 = __logf(pv.y + EPSF) - lg1p;
        float pal2 = __logf(pv.z + EPSF) - lg1p;
        float pal3 = __logf(pv.w + EPSF) - lg1p;
        float4 o;
        if (idx < 500) {
            float4 lv = lrow4[idx];
            float a0 = lv.x - lZo + g, b0 = pal0 + lgm;
            float a1 = lv.y - lZo + g, b1 = pal1 + lgm;
            float a2 = lv.z - lZo + g, b2 = pal2 + lgm;
            float a3 = lv.w - lZo + g, b3 = pal3 + lgm;
            float m0 = fmaxf(a0, b0), m1 = fmaxf(a1, b1);
            float m2 = fmaxf(a2, b2), m3 = fmaxf(a3, b3);
            o.x = m0 + __logf(__expf(a0 - m0) + __expf(b0 - m0));
            o.y = m1 + __logf(__expf(a1 - m1) + __expf(b1 - m1));
            o.z = m2 + __logf(__expf(a2 - m2) + __expf(b2 - m2));
            o.w = m3 + __logf(__expf(a3 - m3) + __expf(b3 - m3));
        } else {
            o.x = pal0 + lgm; o.y = pal1 + lgm;
            o.z = pal2 + lgm; o.w = pal3 + lgm;
        }
        orow4[idx] = o;
    }
}

extern "C" void kernel_launch(void* const* d_in, const int* in_sizes, int n_in,
                              void* d_out, int out_size, void* d_ws, size_t ws_size,
                              hipStream_t stream) {
    const float* out_logits = (const float*)d_in[0];
    const float* feature    = (const float*)d_in[1];
    const float* memory_raw = (const float*)d_in[2];
    const int*   content_e  = (const int*)d_in[3];
    const float* Wq = (const float*)d_in[4];
    const float* bq = (const float*)d_in[5];
    const float* Wk = (const float*)d_in[6];
    const float* bk = (const float*)d_in[7];
    const float* sentinel = (const float*)d_in[8];
    float* out = (float*)d_out;

    u16* memb   = (u16*)d_ws;                             // 16384*512 bf16
    u16* featb  = memb   + (size_t)16384 * 512;           // 4096*512
    u16* wqT    = featb  + (size_t)4096 * 512;            // 512*512
    u16* wkE    = wqT    + (size_t)512 * 512;             // 1280*512
    u16* queryb = wkE    + (size_t)NKE * 512;             // 4096*512
    u16* qkb    = queryb + (size_t)4096 * 512;            // 4096*1280
    float* atten = (float*)(qkb + (size_t)4096 * NKE);    // 4096*2048 f32 (e-values)
    float* logZo = atten + (size_t)4096 * SRC;            // 4096 f32
    int* ce_perm = (int*)(logZo + 4096);                  // 16*2048 int
    float* rowsum = (float*)(ce_perm + (size_t)BSZ * SRC); // 4096 f32

    prep<<<6737, 256, 0, stream>>>(memory_raw, feature, Wq, Wk, sentinel, bk,
                                   out_logits, content_e,
                                   (int4*)memb, (int4*)featb, wqT, wkE, logZo,
                                   ce_perm, rowsum);
    gemm_query<<<dim3(4, 32), 256, 0, stream>>>(featb, wqT, bq, queryb);
    gemm_qk<<<dim3(10, 32), 256, 0, stream>>>(queryb, wkE, qkb);
    gemm_atten<<<dim3(8, 2, 32), 256, 0, stream>>>(qkb, memb, ce_perm, rowsum, atten);
    finalize<<<BSZ * TGT, 256, 0, stream>>>(atten, ce_perm, qkb, rowsum,
                                            out_logits, logZo, out);
}

// Round 8
// 121.175 us; speedup vs baseline: 4.0246x; 1.0185x over previous
//
#include <hip/hip_runtime.h>
#include <math.h>

#define BSZ   16
#define LSEQ  1024
#define TGT   256
#define HID   512
#define TV    2000
#define VOC   3000
#define SRC   2048
#define NKE   1280     // WkE rows: 2 j-halves x 640 (512 d + sentinel + bias + pad)
#define JOFF  640
#define SCALE 0.044194173824159216f   // 1/sqrt(512)

typedef unsigned short u16;
typedef __attribute__((ext_vector_type(8))) short bf16x8;
typedef __attribute__((ext_vector_type(4))) float f32x4;

__device__ __forceinline__ u16 f2bf(float x) {
    unsigned u = __float_as_uint(x);
    u += 0x7FFFu + ((u >> 16) & 1u);
    return (u16)(u >> 16);
}
__device__ __forceinline__ float bf2f(u16 x) {
    return __uint_as_float((unsigned)x << 16);
}

static __device__ __forceinline__ float gelu_exact(float x) {
    return 0.5f * x * (1.0f + erff(x * 0.70710678118654752f));
}

// async 16B global -> LDS (wave-uniform LDS base + lane*16)
__device__ __forceinline__ void gload16(const u16* g, u16* l) {
    __builtin_amdgcn_global_load_lds(
        (const __attribute__((address_space(1))) unsigned int*)g,
        (__attribute__((address_space(3))) unsigned int*)l,
        16, 0, 0);
}

// ---------------- PREP mega-kernel ----------------
// blocks: [0,4096) cast memory_raw | [4096,5120) cast feature | [5120,5376) Wq^T |
//         [5376,5696) WkE build | [5696,6720) k_logz | [6720,6736) ce_perm | 6736 rowsum=0
__device__ __forceinline__ void cast8_body(const float4* __restrict__ in,
                                           int4* __restrict__ out, int i) {
    float4 x = in[2 * i], y = in[2 * i + 1];
    unsigned p0 = (unsigned)f2bf(x.x) | ((unsigned)f2bf(x.y) << 16);
    unsigned p1 = (unsigned)f2bf(x.z) | ((unsigned)f2bf(x.w) << 16);
    unsigned p2 = (unsigned)f2bf(y.x) | ((unsigned)f2bf(y.y) << 16);
    unsigned p3 = (unsigned)f2bf(y.z) | ((unsigned)f2bf(y.w) << 16);
    out[i] = make_int4(p0, p1, p2, p3);
}

__global__ __launch_bounds__(256) void prep(
    const float* __restrict__ memory_raw, const float* __restrict__ feature,
    const float* __restrict__ Wq, const float* __restrict__ Wk,
    const float* __restrict__ sentinel, const float* __restrict__ bk,
    const float* __restrict__ logits, const int* __restrict__ ce,
    int4* __restrict__ memb, int4* __restrict__ featb,
    u16* __restrict__ wqT, u16* __restrict__ wkE,
    float* __restrict__ logZo, int* __restrict__ ce_perm,
    float* __restrict__ rowsum)
{
    __shared__ float t[32][33];
    const int id = blockIdx.x;
    const int tid = threadIdx.x;
    if (id < 4096) {
        cast8_body((const float4*)memory_raw, memb, id * 256 + tid);
    } else if (id < 5120) {
        cast8_body((const float4*)feature, featb, (id - 4096) * 256 + tid);
    } else if (id < 5376) {
        // Wq^T (512x512)
        int id2 = id - 5120;
        int bx = (id2 & 15) * 32, by = (id2 >> 4) * 32;
        const int tx = tid & 31, ty = tid >> 5;
        #pragma unroll
        for (int k = 0; k < 4; ++k)
            t[ty + 8 * k][tx] = Wq[(size_t)(by + ty + 8 * k) * 512 + bx + tx];
        __syncthreads();
        #pragma unroll
        for (int k = 0; k < 4; ++k)
            wqT[(size_t)(bx + ty + 8 * k) * 512 + by + tx] = f2bf(t[tx][ty + 8 * k]);
    } else if (id < 5696) {
        // WkE build: 4 rows per block, 64 threads x 8 cols per row
        const int rr = (id - 5376) * 4 + (tid >> 6);   // 0..1279
        const int c = (tid & 63) * 8;
        const int j = rr >= JOFF;
        const int dd = rr - j * JOFF;
        u16* dst = wkE + (size_t)rr * HID + c;
        if (dd < 512) {
            const float* src = Wk + (size_t)dd * 1024 + j * 512 + c;
            #pragma unroll
            for (int k = 0; k < 8; ++k) dst[k] = f2bf(src[k]);
        } else if (dd == 512) {
            #pragma unroll
            for (int k = 0; k < 8; ++k) dst[k] = f2bf(sentinel[c + k]);
        } else if (dd == 513) {
            #pragma unroll
            for (int k = 0; k < 8; ++k) dst[k] = f2bf(bk[j * 512 + c + k]);
        } else {
            #pragma unroll
            for (int k = 0; k < 8; ++k) dst[k] = 0;
        }
    } else if (id < 6720) {
        // k_logz: 4 rows per block, one wave per row (TV = 500 float4)
        const int row = (id - 5696) * 4 + (tid >> 6);
        const int lane = tid & 63;
        const float4* lrow4 = (const float4*)(logits + (size_t)row * TV);
        float4 v4[8];
        float m = -INFINITY;
        #pragma unroll
        for (int i = 0; i < 8; ++i) {
            int idx = lane + 64 * i;
            if (idx < 500) {
                v4[i] = lrow4[idx];
                m = fmaxf(m, fmaxf(fmaxf(v4[i].x, v4[i].y), fmaxf(v4[i].z, v4[i].w)));
            } else {
                v4[i] = make_float4(-INFINITY, -INFINITY, -INFINITY, -INFINITY);
            }
        }
        #pragma unroll
        for (int o = 32; o > 0; o >>= 1) m = fmaxf(m, __shfl_xor(m, o, 64));
        float s = 0.f;
        #pragma unroll
        for (int i = 0; i < 8; ++i) {
            s += __expf(v4[i].x - m) + __expf(v4[i].y - m)
               + __expf(v4[i].z - m) + __expf(v4[i].w - m);
        }
        #pragma unroll
        for (int o = 32; o > 0; o >>= 1) s += __shfl_xor(s, o, 64);
        if (lane == 0) logZo[row] = m + __logf(s);
    } else if (id < 6736) {
        // ce_perm: ce_perm[b][j*1024+l] = ce[b][2l+j]
        const int b = id - 6720;
        const int* ceb = ce + (size_t)b * SRC;
        int* cpb = ce_perm + (size_t)b * SRC;
        for (int jl = tid; jl < SRC; jl += 256) {
            int j = jl >> 10, l = jl & 1023;
            cpb[jl] = ceb[2 * l + j];
        }
    } else {
        // zero rowsum (4096 f32 = 1024 float4) — fresh every launch
        float4* rz = (float4*)rowsum;
        for (int i = tid; i < 1024; i += 256) rz[i] = make_float4(0.f, 0.f, 0.f, 0.f);
    }
}

// ---------------- MFMA GEMM body: C = A[M,512] . B^T[N,512], 128x128 tile ----------------
// EPI 1: query (+bq, gelu) -> bf16 [m][512]
// EPI 3: qk (plain)        -> bf16 [m][1280]
// EPI 2: atten (bias + scale + EXP + mask + row-partial-sum) -> bf16 e-values, z=(b,jj)
template<int EPI, int LDA>
__device__ __forceinline__ void gemm_body(
    int m0, int n0, int z,
    const u16* __restrict__ Abase, const u16* __restrict__ Bbase,
    const float* __restrict__ bias, u16* __restrict__ outb,
    const int* __restrict__ ce_perm, float* __restrict__ rowsum,
    u16* __restrict__ As, u16* __restrict__ Bs)   // each 2*4096 u16
{
    const int tid = threadIdx.x;
    const int lane = tid & 63;
    const int w = tid >> 6;
    const int wr = (w >> 1) * 64, wc = (w & 1) * 64;

    const u16* Ag = Abase;
    const u16* Bg = Bbase;
    if (EPI == 2) {
        Ag = Abase + (size_t)(z >> 1) * TGT * NKE + (size_t)(z & 1) * JOFF;
        Bg = Bbase + (size_t)(z >> 1) * LSEQ * HID;
    }

    const int chunkrow = lane >> 2;
    const int colc = (lane & 3) * 8;
    const int c0 = w * 2, c1 = c0 + 1;
    const u16* gA0 = Ag + (size_t)(m0 + c0 * 16 + chunkrow) * LDA + colc;
    const u16* gA1 = Ag + (size_t)(m0 + c1 * 16 + chunkrow) * LDA + colc;
    const u16* gB0 = Bg + (size_t)(n0 + c0 * 16 + chunkrow) * HID + colc;
    const u16* gB1 = Bg + (size_t)(n0 + c1 * 16 + chunkrow) * HID + colc;

    const int la = lane & 15, lb = lane >> 4;
    f32x4 acc[4][4] = {};

    gload16(gA0, As + c0 * 512);
    gload16(gA1, As + c1 * 512);
    gload16(gB0, Bs + c0 * 512);
    gload16(gB1, Bs + c1 * 512);

    int cur = 0;
    for (int k0 = 0; k0 < HID; k0 += 32) {
        __syncthreads();   // drains vmcnt(0) (stage complete) + barrier
        const u16* Asb = As + cur * 4096;
        const u16* Bsb = Bs + cur * 4096;
        bf16x8 af[4], bfv[4];
        #pragma unroll
        for (int i = 0; i < 4; ++i)
            af[i] = *(const bf16x8*)(Asb + (wr + i * 16 + la) * 32 + lb * 8);
        #pragma unroll
        for (int j = 0; j < 4; ++j)
            bfv[j] = *(const bf16x8*)(Bsb + (wc + j * 16 + la) * 32 + lb * 8);
        if (k0 + 32 < HID) {
            const int nb = cur ^ 1;
            u16* An = As + nb * 4096;
            u16* Bn = Bs + nb * 4096;
            gload16(gA0 + k0 + 32, An + c0 * 512);
            gload16(gA1 + k0 + 32, An + c1 * 512);
            gload16(gB0 + k0 + 32, Bn + c0 * 512);
            gload16(gB1 + k0 + 32, Bn + c1 * 512);
        }
        #pragma unroll
        for (int i = 0; i < 4; ++i)
            #pragma unroll
            for (int j = 0; j < 4; ++j)
                acc[i][j] = __builtin_amdgcn_mfma_f32_16x16x32_bf16(af[i], bfv[j], acc[i][j], 0, 0, 0);
        cur ^= 1;
    }

    const int r_l = (lane >> 4) * 4, c_l = lane & 15;
    if (EPI == 1) {
        #pragma unroll
        for (int j = 0; j < 4; ++j) {
            const int n = n0 + wc + j * 16 + c_l;
            const float bv = bias[n];
            #pragma unroll
            for (int i = 0; i < 4; ++i)
                #pragma unroll
                for (int r = 0; r < 4; ++r) {
                    const int m = m0 + wr + i * 16 + r_l + r;
                    outb[(size_t)m * HID + n] = f2bf(gelu_exact(acc[i][j][r] + bv));
                }
        }
    } else if (EPI == 3) {
        #pragma unroll
        for (int j = 0; j < 4; ++j) {
            const int n = n0 + wc + j * 16 + c_l;
            #pragma unroll
            for (int i = 0; i < 4; ++i)
                #pragma unroll
                for (int r = 0; r < 4; ++r) {
                    const int m = m0 + wr + i * 16 + r_l + r;
                    outb[(size_t)m * NKE + n] = f2bf(acc[i][j][r]);
                }
        }
    } else {
        const int b = z >> 1, jj = z & 1;
        // per-row bias (q.bk_j) gathered from qk row; per-col mask from ce_perm
        float biasr[4][4];
        #pragma unroll
        for (int i = 0; i < 4; ++i)
            #pragma unroll
            for (int r = 0; r < 4; ++r) {
                const int tt = m0 + wr + i * 16 + r_l + r;
                biasr[i][r] = bf2f(Abase[(size_t)(b * TGT + tt) * NKE + jj * JOFF + 513]);
            }
        int cj[4];
        #pragma unroll
        for (int j = 0; j < 4; ++j)
            cj[j] = ce_perm[(size_t)b * SRC + jj * 1024 + n0 + wc + j * 16 + c_l];
        #pragma unroll
        for (int i = 0; i < 4; ++i)
            #pragma unroll
            for (int r = 0; r < 4; ++r) {
                const int tt = m0 + wr + i * 16 + r_l + r;
                float rs = 0.f;
                #pragma unroll
                for (int j = 0; j < 4; ++j) {
                    const int l = n0 + wc + j * 16 + c_l;
                    float ev = (cj[j] == 0) ? 0.f
                             : __expf((acc[i][j][r] + biasr[i][r]) * SCALE);
                    outb[(size_t)(b * TGT + tt) * SRC + jj * 1024 + l] = f2bf(ev);
                    rs += ev;
                }
                rs += __shfl_xor(rs, 1, 64);
                rs += __shfl_xor(rs, 2, 64);
                rs += __shfl_xor(rs, 4, 64);
                rs += __shfl_xor(rs, 8, 64);
                if (c_l == 0) atomicAdd(&rowsum[b * TGT + tt], rs);
            }
    }
}

__global__ __launch_bounds__(256) void gemm_query(
    const u16* __restrict__ feat, const u16* __restrict__ wqT,
    const float* __restrict__ bq, u16* __restrict__ queryb)
{
    __shared__ u16 As[2 * 4096];
    __shared__ u16 Bs[2 * 4096];
    gemm_body<1, 512>(blockIdx.y * 128, blockIdx.x * 128, 0,
                      feat, wqT, bq, queryb, nullptr, nullptr, As, Bs);
}

__global__ __launch_bounds__(256) void gemm_qk(
    const u16* __restrict__ queryb, const u16* __restrict__ wkE,
    u16* __restrict__ qkb)
{
    __shared__ u16 As[2 * 4096];
    __shared__ u16 Bs[2 * 4096];
    gemm_body<3, 512>(blockIdx.y * 128, blockIdx.x * 128, 0,
                      queryb, wkE, nullptr, qkb, nullptr, nullptr, As, Bs);
}

__global__ __launch_bounds__(256) void gemm_atten(
    const u16* __restrict__ qkb, const u16* __restrict__ memb,
    const int* __restrict__ ce_perm, float* __restrict__ rowsum,
    u16* __restrict__ atten_e)
{
    __shared__ u16 As[2 * 4096];
    __shared__ u16 Bs[2 * 4096];
    gemm_body<2, NKE>(blockIdx.y * 128, blockIdx.x * 128, blockIdx.z,
                      qkb, memb, nullptr, atten_e, ce_perm, rowsum, As, Bs);
}

// ---------------- finalize: per (b,t) row, branchless scatter + 2-trans combine ----------------
__global__ __launch_bounds__(256) void finalize(
    const u16* __restrict__ atten_e, const int* __restrict__ ce_perm,
    const u16* __restrict__ qkb, const float* __restrict__ rowsum,
    const float* __restrict__ out_logits, const float* __restrict__ logZo,
    float* __restrict__ out)
{
    __shared__ float p[VOC];
    const int bt = blockIdx.x;
    const int b = bt >> 8;
    const int tid = threadIdx.x;   // 0..255
    const float EPSF = 1.1920929e-07f;

    float4* p4 = (float4*)p;
    #pragma unroll
    for (int k = 0; k < 3; ++k) {
        int idx = tid + 256 * k;
        if (idx < 750) p4[idx] = make_float4(0.f, 0.f, 0.f, 0.f);
    }

    // row stats from precomputed rowsum (no block reductions)
    const float sent_v = bf2f(qkb[(size_t)bt * NKE + 512]) * SCALE;
    const float se = __expf(sent_v);
    const float sm = rowsum[bt] + se;
    const float inv = 1.0f / sm;
    const float g = sent_v - __logf(sm);   // log gate
    const float eg = se * inv;
    const float dl = __logf(1.0f - eg + EPSF) - log1pf(-eg + EPSF);  // ~0 (rounding)
    const float edl = __expf(dl);
    const float gZ = g - logZo[bt];

    // this thread's 8 e-values (bf16) and 8 scatter ids — branchless atomics
    const int4 ev4 = ((const int4*)(atten_e + (size_t)bt * SRC))[tid];
    const int4 c40 = ((const int4*)(ce_perm + (size_t)b * SRC))[2 * tid];
    const int4 c41 = ((const int4*)(ce_perm + (size_t)b * SRC))[2 * tid + 1];
    __syncthreads();
    atomicAdd(&p[c40.x], bf2f((u16)(ev4.x & 0xffff)) * inv);
    atomicAdd(&p[c40.y], bf2f((u16)((unsigned)ev4.x >> 16)) * inv);
    atomicAdd(&p[c40.z], bf2f((u16)(ev4.y & 0xffff)) * inv);
    atomicAdd(&p[c40.w], bf2f((u16)((unsigned)ev4.y >> 16)) * inv);
    atomicAdd(&p[c41.x], bf2f((u16)(ev4.z & 0xffff)) * inv);
    atomicAdd(&p[c41.y], bf2f((u16)((unsigned)ev4.z >> 16)) * inv);
    atomicAdd(&p[c41.z], bf2f((u16)(ev4.w & 0xffff)) * inv);
    atomicAdd(&p[c41.w], bf2f((u16)((unsigned)ev4.w >> 16)) * inv);
    __syncthreads();

    const float4* lrow4 = (const float4*)(out_logits + (size_t)bt * TV);
    float4* orow4 = (float4*)(out + (size_t)bt * VOC);
    #pragma unroll
    for (int k = 0; k < 3; ++k) {
        int idx = tid + 256 * k;
        if (idx >= 750) continue;
        float4 pv = p4[idx];
        float4 o;
        if (idx < 500) {
            float4 lv = lrow4[idx];
            o.x = __logf(__expf(lv.x + gZ) + (pv.x + EPSF) * edl);
            o.y = __logf(__expf(lv.y + gZ) + (pv.y + EPSF) * edl);
            o.z = __logf(__expf(lv.z + gZ) + (pv.z + EPSF) * edl);
            o.w = __logf(__expf(lv.w + gZ) + (pv.w + EPSF) * edl);
        } else {
            o.x = __logf(pv.x + EPSF) + dl;
            o.y = __logf(pv.y + EPSF) + dl;
            o.z = __logf(pv.z + EPSF) + dl;
            o.w = __logf(pv.w + EPSF) + dl;
        }
        orow4[idx] = o;
    }
}

extern "C" void kernel_launch(void* const* d_in, const int* in_sizes, int n_in,
                              void* d_out, int out_size, void* d_ws, size_t ws_size,
                              hipStream_t stream) {
    const float* out_logits = (const float*)d_in[0];
    const float* feature    = (const float*)d_in[1];
    const float* memory_raw = (const float*)d_in[2];
    const int*   content_e  = (const int*)d_in[3];
    const float* Wq = (const float*)d_in[4];
    const float* bq = (const float*)d_in[5];
    const float* Wk = (const float*)d_in[6];
    const float* bk = (const float*)d_in[7];
    const float* sentinel = (const float*)d_in[8];
    float* out = (float*)d_out;

    u16* memb   = (u16*)d_ws;                             // 16384*512 bf16
    u16* featb  = memb   + (size_t)16384 * 512;           // 4096*512
    u16* wqT    = featb  + (size_t)4096 * 512;            // 512*512
    u16* wkE    = wqT    + (size_t)512 * 512;             // 1280*512
    u16* queryb = wkE    + (size_t)NKE * 512;             // 4096*512
    u16* qkb    = queryb + (size_t)4096 * 512;            // 4096*1280
    u16* atten_eb = qkb  + (size_t)4096 * NKE;            // 4096*2048 bf16 e-values
    float* logZo = (float*)(atten_eb + (size_t)4096 * SRC); // 4096 f32
    int* ce_perm = (int*)(logZo + 4096);                  // 16*2048 int
    float* rowsum = (float*)(ce_perm + (size_t)BSZ * SRC); // 4096 f32

    prep<<<6737, 256, 0, stream>>>(memory_raw, feature, Wq, Wk, sentinel, bk,
                                   out_logits, content_e,
                                   (int4*)memb, (int4*)featb, wqT, wkE, logZo,
                                   ce_perm, rowsum);
    gemm_query<<<dim3(4, 32), 256, 0, stream>>>(featb, wqT, bq, queryb);
    gemm_qk<<<dim3(10, 32), 256, 0, stream>>>(queryb, wkE, qkb);
    gemm_atten<<<dim3(8, 2, 32), 256, 0, stream>>>(qkb, memb, ce_perm, rowsum, atten_eb);
    finalize<<<BSZ * TGT, 256, 0, stream>>>(atten_eb, ce_perm, qkb, rowsum,
                                            out_logits, logZo, out);
}